// Round 13
// baseline (750.245 us; speedup 1.0000x reference)
//
#include <hip/hip_runtime.h>

#define NN 100000
#define NE 1600000
#define EPS_BN 1e-5f
#define NP 391      // ceil(NN/256) scan partials
#define NB 32       // dst buckets
#define BW 3125     // NN / NB
#define CAP 53248   // bucket capacity (avg 50000), 13*4096

typedef __attribute__((ext_vector_type(8))) short short8v;
typedef __attribute__((ext_vector_type(4))) float f32x4;

__device__ __forceinline__ unsigned short f2bf(float f) {
    unsigned u = __float_as_uint(f);
    u += 0x7fff + ((u >> 16) & 1);          // RTNE
    return (unsigned short)(u >> 16);
}
__device__ __forceinline__ float bf2f(unsigned short h) {
    return __uint_as_float((unsigned)h << 16);
}

// ---------------- init: cnt zero, stats2 zero, cursors ----------------
__global__ void k_init(int* __restrict__ cnt, float* __restrict__ stats2,
                       int* __restrict__ cursors) {
    int i = blockIdx.x * 256 + threadIdx.x;
    if (i < NN) cnt[i] = 0;
    if (i < 64 * 256) stats2[i] = 0.f;
    if (i < NB) cursors[i] = i * CAP;
}

// Phase A: partition edges into 32 dst-range buckets, (dst,src) pairs.
__global__ __launch_bounds__(256) void k_part(const int* __restrict__ src,
                                              const int* __restrict__ dst,
                                              int* __restrict__ cursors,
                                              int2* __restrict__ part) {
    __shared__ int lh[4][NB];     // per-wave hist, then per-wave fill cursor
    __shared__ int lo[4][NB];     // per-wave base offset
    int t = threadIdx.x;
    int w = t >> 6;
    if (t < 128) lh[t >> 5][t & 31] = 0;
    __syncthreads();
    int base = blockIdx.x * 4096;
    int d[16], s[16], b[16];
    #pragma unroll 16
    for (int it = 0; it < 16; ++it) {
        int e = base + it * 256 + t;
        if (e < NE) {
            d[it] = dst[e];
            s[it] = src[e];
            b[it] = d[it] / BW;
            atomicAdd(&lh[w][b[it]], 1);
        } else b[it] = -1;
    }
    __syncthreads();
    if (t < NB) {
        int c0 = lh[0][t], c1 = lh[1][t], c2 = lh[2][t], c3 = lh[3][t];
        int tot = c0 + c1 + c2 + c3;
        int bb = atomicAdd(&cursors[t], tot);
        lo[0][t] = bb;
        lo[1][t] = bb + c0;
        lo[2][t] = bb + c0 + c1;
        lo[3][t] = bb + c0 + c1 + c2;
        lh[0][t] = 0; lh[1][t] = 0; lh[2][t] = 0; lh[3][t] = 0;
    }
    __syncthreads();
    #pragma unroll 16
    for (int it = 0; it < 16; ++it) {
        if (b[it] >= 0) {
            int pos = lo[w][b[it]] + atomicAdd(&lh[w][b[it]], 1);
            part[pos] = make_int2(d[it], s[it]);
        }
    }
}

// Phase B: per-bucket histogram; bucket b&31 stays on one XCD -> cnt slice L2-local.
__global__ void k_hist32(const int* __restrict__ cursors, const int2* __restrict__ part,
                         int* __restrict__ cnt) {
    int b = blockIdx.x & 31, chunk = blockIdx.x >> 5;
    int n = cursors[b] - b * CAP;
    const int2* p = part + (size_t)b * CAP;
    int i = chunk * 4096 + threadIdx.x;
    #pragma unroll 16
    for (int it = 0; it < 16; ++it, i += 256)
        if (i < n) atomicAdd(&cnt[p[i].x], 1);
}

__global__ __launch_bounds__(256) void k_scan1(const int* __restrict__ cnt,
                                               int* __restrict__ rowptr,
                                               int* __restrict__ partial,
                                               float* __restrict__ dinv) {
    __shared__ int sh[256];
    int i = blockIdx.x * 256 + threadIdx.x;
    int v = (i < NN) ? cnt[i] : 0;
    if (i < NN) dinv[i] = rsqrtf((float)(v + 1));         // +1 self-loop
    sh[threadIdx.x] = v;
    __syncthreads();
    for (int off = 1; off < 256; off <<= 1) {
        int t = (threadIdx.x >= off) ? sh[threadIdx.x - off] : 0;
        __syncthreads();
        sh[threadIdx.x] += t;
        __syncthreads();
    }
    if (i < NN) rowptr[i] = sh[threadIdx.x] - v;           // exclusive
    if (threadIdx.x == 255) partial[blockIdx.x] = sh[255]; // block total
}

__global__ __launch_bounds__(512) void k_scan2(int* __restrict__ partial) {
    __shared__ int sh[512];
    int tid = threadIdx.x;
    int v = (tid < NP) ? partial[tid] : 0;
    sh[tid] = v;
    __syncthreads();
    for (int off = 1; off < 512; off <<= 1) {
        int t = (tid >= off) ? sh[tid - off] : 0;
        __syncthreads();
        sh[tid] += t;
        __syncthreads();
    }
    if (tid < NP) partial[tid] = sh[tid] - v;              // exclusive
}

__global__ void k_scan3(int* __restrict__ rowptr, const int* __restrict__ partial,
                        int* __restrict__ fill) {
    int i = blockIdx.x * 256 + threadIdx.x;
    if (i < NN) {
        int v = rowptr[i] + partial[blockIdx.x];
        rowptr[i] = v;
        fill[i] = v;                                       // fill cursor = row start
    }
    if (i == 0) rowptr[NN] = NE;
}

// Phase C: per-bucket CSR fill (col only); cecol slice ~200KB stays in XCD L2.
__global__ void k_fill32(const int* __restrict__ cursors, const int2* __restrict__ part,
                         int* __restrict__ fill, int* __restrict__ cecol) {
    int b = blockIdx.x & 31, chunk = blockIdx.x >> 5;
    int n = cursors[b] - b * CAP;
    const int2* p = part + (size_t)b * CAP;
    int i = chunk * 4096 + threadIdx.x;
    #pragma unroll 16
    for (int it = 0; it < 16; ++it, i += 256) {
        if (i < n) {
            int2 e = p[i];
            int pos = atomicAdd(&fill[e.x], 1);
            cecol[pos] = e.y;
        }
    }
}

// ---------------- fused weight convert: W0,W1 -> Wt[c][k]; W2 -> [64][128] padded --
__global__ void k_wconvall(const float* __restrict__ W0, const float* __restrict__ W1,
                           const float* __restrict__ W2,
                           unsigned short* __restrict__ Wt0,
                           unsigned short* __restrict__ Wt1,
                           unsigned short* __restrict__ Wt2) {
    int idx = blockIdx.x * 256 + threadIdx.x;
    if (idx < 16384) {
        int k = idx >> 7, c = idx & 127;
        Wt0[c * 128 + k] = f2bf(W0[idx]);
    } else if (idx < 32768) {
        int j = idx - 16384;
        int k = j >> 7, c = j & 127;
        Wt1[c * 128 + k] = f2bf(W1[j]);
    } else if (idx < 32768 + 8192) {
        int j = idx - 32768;
        int c = j >> 7, k = j & 127;
        Wt2[j] = (c < 40) ? f2bf(W2[k * 40 + c]) : (unsigned short)0;
    }
}

#define XPAD 136   // LDS row stride in ushorts: 272B = 68 words, 68%32=4 -> 2-way max
#define SLN ((size_t)NN * 16)   // elements per feature slice

// ---------------- MFMA GEMM (layer 0): f32 input, slice-major dinv-scaled out ------
__global__ __launch_bounds__(256) void k_gemm128_f(
    const float* __restrict__ in, const unsigned short* __restrict__ Wt,
    unsigned short* __restrict__ outs, const float* __restrict__ dinv) {
    __shared__ unsigned short xs[32 * XPAD];
    __shared__ float dsv[32];
    const int tid = threadIdx.x;
    const int row0 = blockIdx.x * 32;
    if (tid < 32) dsv[tid] = dinv[row0 + tid];
    for (int i = tid; i < 1024; i += 256) {
        float4 v = ((const float4*)(in + (size_t)row0 * 128))[i];
        int c4 = (i & 31) * 4;
        ushort4 b;
        b.x = f2bf(v.x); b.y = f2bf(v.y); b.z = f2bf(v.z); b.w = f2bf(v.w);
        *(ushort4*)&xs[(i >> 5) * XPAD + c4] = b;
    }
    __syncthreads();

    const int w = tid >> 6;
    const int L = tid & 63;
    const int l15 = L & 15;
    const int l4 = L >> 4;
    f32x4 acc[2][2] = {{{0.f, 0.f, 0.f, 0.f}, {0.f, 0.f, 0.f, 0.f}},
                       {{0.f, 0.f, 0.f, 0.f}, {0.f, 0.f, 0.f, 0.f}}};
    const unsigned short* Wb0 = Wt + (size_t)(w * 32 + l15) * 128;
    const unsigned short* Wb1 = Wt + (size_t)(w * 32 + 16 + l15) * 128;
    #pragma unroll
    for (int kk = 0; kk < 4; ++kk) {
        int k0 = kk * 32 + l4 * 8;
        short8v a0 = *(const short8v*)&xs[l15 * XPAD + k0];
        short8v a1 = *(const short8v*)&xs[(16 + l15) * XPAD + k0];
        short8v b0 = *(const short8v*)&Wb0[k0];
        short8v b1 = *(const short8v*)&Wb1[k0];
        acc[0][0] = __builtin_amdgcn_mfma_f32_16x16x32_bf16(a0, b0, acc[0][0], 0, 0, 0);
        acc[0][1] = __builtin_amdgcn_mfma_f32_16x16x32_bf16(a0, b1, acc[0][1], 0, 0, 0);
        acc[1][0] = __builtin_amdgcn_mfma_f32_16x16x32_bf16(a1, b0, acc[1][0], 0, 0, 0);
        acc[1][1] = __builtin_amdgcn_mfma_f32_16x16x32_bf16(a1, b1, acc[1][1], 0, 0, 0);
    }
    #pragma unroll
    for (int h = 0; h < 2; ++h)
        #pragma unroll
        for (int c = 0; c < 2; ++c) {
            int colg = w * 32 + c * 16 + l15;
            unsigned short* op = outs + (size_t)(colg >> 4) * SLN + (colg & 15);
            #pragma unroll
            for (int r = 0; r < 4; ++r) {
                int rl = h * 16 + l4 * 4 + r;
                op[(size_t)(row0 + rl) * 16] = f2bf(acc[h][c][r] * dsv[rl]);
            }
        }
}

// ------ MFMA GEMM (layer 1): slice-major bf16 in + BN+ReLU, slice-major out --------
__global__ __launch_bounds__(256) void k_gemm128_b(
    const unsigned short* __restrict__ ins, const unsigned short* __restrict__ Wt,
    unsigned short* __restrict__ outs,
    const float* __restrict__ bnsc, const float* __restrict__ bnsh,
    const float* __restrict__ dinv) {
    __shared__ unsigned short xs[32 * XPAD];
    __shared__ float dsv[32];
    const int tid = threadIdx.x;
    const int row0 = blockIdx.x * 32;
    if (tid < 32) dsv[tid] = dinv[row0 + tid];
    for (int i = tid; i < 512; i += 256) {
        int r = i & 31, c8 = (i >> 5) * 8;
        short8v u = *(const short8v*)(ins + (size_t)(c8 >> 4) * SLN
                                      + (size_t)(row0 + r) * 16 + (c8 & 15));
        short8v o;
        #pragma unroll
        for (int j = 0; j < 8; ++j) {
            float v = bf2f((unsigned short)u[j]);
            v = fmaxf(v * bnsc[c8 + j] + bnsh[c8 + j], 0.f);
            o[j] = (short)f2bf(v);
        }
        *(short8v*)&xs[r * XPAD + c8] = o;
    }
    __syncthreads();

    const int w = tid >> 6;
    const int L = tid & 63;
    const int l15 = L & 15;
    const int l4 = L >> 4;
    f32x4 acc[2][2] = {{{0.f, 0.f, 0.f, 0.f}, {0.f, 0.f, 0.f, 0.f}},
                       {{0.f, 0.f, 0.f, 0.f}, {0.f, 0.f, 0.f, 0.f}}};
    const unsigned short* Wb0 = Wt + (size_t)(w * 32 + l15) * 128;
    const unsigned short* Wb1 = Wt + (size_t)(w * 32 + 16 + l15) * 128;
    #pragma unroll
    for (int kk = 0; kk < 4; ++kk) {
        int k0 = kk * 32 + l4 * 8;
        short8v a0 = *(const short8v*)&xs[l15 * XPAD + k0];
        short8v a1 = *(const short8v*)&xs[(16 + l15) * XPAD + k0];
        short8v b0 = *(const short8v*)&Wb0[k0];
        short8v b1 = *(const short8v*)&Wb1[k0];
        acc[0][0] = __builtin_amdgcn_mfma_f32_16x16x32_bf16(a0, b0, acc[0][0], 0, 0, 0);
        acc[0][1] = __builtin_amdgcn_mfma_f32_16x16x32_bf16(a0, b1, acc[0][1], 0, 0, 0);
        acc[1][0] = __builtin_amdgcn_mfma_f32_16x16x32_bf16(a1, b0, acc[1][0], 0, 0, 0);
        acc[1][1] = __builtin_amdgcn_mfma_f32_16x16x32_bf16(a1, b1, acc[1][1], 0, 0, 0);
    }
    #pragma unroll
    for (int h = 0; h < 2; ++h)
        #pragma unroll
        for (int c = 0; c < 2; ++c) {
            int colg = w * 32 + c * 16 + l15;
            unsigned short* op = outs + (size_t)(colg >> 4) * SLN + (colg & 15);
            #pragma unroll
            for (int r = 0; r < 4; ++r) {
                int rl = h * 16 + l4 * 4 + r;
                op[(size_t)(row0 + rl) * 16] = f2bf(acc[h][c][r] * dsv[rl]);
            }
        }
}

// --- MFMA GEMM (layer 2): slice-major in + BN+ReLU, out[N,64] bf16 linear ---------
__global__ __launch_bounds__(256) void k_gemm40_mfma(
    const unsigned short* __restrict__ ins, const unsigned short* __restrict__ Wt,
    unsigned short* __restrict__ outb,
    const float* __restrict__ bnsc, const float* __restrict__ bnsh,
    const float* __restrict__ dinv) {
    __shared__ unsigned short xs[64 * XPAD];
    __shared__ float dsv[64];
    const int tid = threadIdx.x;
    const int row0 = blockIdx.x * 64;
    if (tid < 64) dsv[tid] = (row0 + tid < NN) ? dinv[row0 + tid] : 0.f;
    for (int i = tid; i < 1024; i += 256) {
        int r = i & 63, c8 = (i >> 6) * 8;
        short8v u = {0, 0, 0, 0, 0, 0, 0, 0};
        if (row0 + r < NN)
            u = *(const short8v*)(ins + (size_t)(c8 >> 4) * SLN
                                  + (size_t)(row0 + r) * 16 + (c8 & 15));
        short8v o;
        #pragma unroll
        for (int j = 0; j < 8; ++j) {
            float v = bf2f((unsigned short)u[j]);
            v = fmaxf(v * bnsc[c8 + j] + bnsh[c8 + j], 0.f);
            o[j] = (short)f2bf(v);
        }
        *(short8v*)&xs[r * XPAD + c8] = o;
    }
    __syncthreads();

    const int w = tid >> 6;
    const int L = tid & 63;
    const int l15 = L & 15;
    const int l4 = L >> 4;
    f32x4 acc[4] = {{0.f, 0.f, 0.f, 0.f}, {0.f, 0.f, 0.f, 0.f},
                    {0.f, 0.f, 0.f, 0.f}, {0.f, 0.f, 0.f, 0.f}};
    #pragma unroll
    for (int kk = 0; kk < 4; ++kk) {
        int k0 = kk * 32 + l4 * 8;
        short8v a = *(const short8v*)&xs[(w * 16 + l15) * XPAD + k0];
        #pragma unroll
        for (int cgi = 0; cgi < 4; ++cgi) {
            short8v b = *(const short8v*)&Wt[(size_t)(cgi * 16 + l15) * 128 + k0];
            acc[cgi] = __builtin_amdgcn_mfma_f32_16x16x32_bf16(a, b, acc[cgi], 0, 0, 0);
        }
    }
    #pragma unroll
    for (int cgi = 0; cgi < 4; ++cgi) {
        int colg = cgi * 16 + l15;
        #pragma unroll
        for (int r = 0; r < 4; ++r) {
            int rl = w * 16 + l4 * 4 + r;
            if (row0 + rl < NN)
                outb[(size_t)(row0 + rl) * 64 + colg] = f2bf(acc[cgi][r] * dsv[rl]);
        }
    }
}

// ------- CSR gather F=128, feature-sliced + XCD-pinned: slice = blockIdx & 7 ------
// hs/as are slice-major [8][NN][16] bf16; slice working set 3.2MB fits XCD L2.
// wave = 2 nodes x (16 edge-groups x 2 lanes, 16B loads); convergent shfl idx.
__global__ __launch_bounds__(256) void k_gather128s(
    const unsigned short* __restrict__ hs, const float* __restrict__ dinv,
    const int* __restrict__ rowptr, const int* __restrict__ cecol,
    const float* __restrict__ bias, unsigned short* __restrict__ as_,
    float* __restrict__ stats2) {
    __shared__ float comb[4][32];
    const int s = blockIdx.x & 7;
    const int chunk = blockIdx.x >> 3;
    const int w = threadIdx.x >> 6;
    const int lane = threadIdx.x & 63;
    const int h = lane >> 5;          // node half 0/1
    const int l = lane & 31;
    const int grp = l >> 1;           // edge group 0..15
    const int p = l & 1;              // col half (8 cols, 16B)
    const int node = chunk * 8 + w * 2 + h;
    const unsigned short* hbs = hs + (size_t)s * SLN;

    float acc[8] = {};
    const int e0 = rowptr[node];
    const int ne = rowptr[node + 1] - e0;           // uniform within half
    const int neo = __shfl_xor(ne, 32);
    const int nmax = max(ne, neo);                  // wave-uniform
    for (int cb = 0; cb < nmax; cb += 32) {         // wave-uniform chunk loop
        int idx = cecol[e0 + min(cb + l, max(ne - 1, 0))];
        idx = min(max(idx, 0), NN - 1);             // safety clamp
        #pragma unroll
        for (int r = 0; r < 2; ++r) {
            if (cb + r * 16 >= nmax) break;         // wave-uniform
            int j = r * 16 + grp;
            int srcl = (h << 5) + min(j, max(ne - 1 - cb, 0));
            int se = __shfl(idx, srcl);             // convergent
            short8v v = *(const short8v*)(hbs + (size_t)se * 16 + p * 8);
            if (cb + j < ne) {
                #pragma unroll
                for (int q = 0; q < 8; ++q) acc[q] += bf2f((unsigned short)v[q]);
            }
        }
    }
    // butterfly over 16 edge-groups (masks preserve h and p)
    #pragma unroll
    for (int q = 0; q < 8; ++q) {
        acc[q] += __shfl_xor(acc[q], 2);
        acc[q] += __shfl_xor(acc[q], 4);
        acc[q] += __shfl_xor(acc[q], 8);
        acc[q] += __shfl_xor(acc[q], 16);
    }
    // self-loop + finalize (valid on every lane: butterfly gave all lanes totals)
    float dn = dinv[node];
    short8v own = *(const short8v*)(hbs + (size_t)node * 16 + p * 8);
    float fin[8];
    #pragma unroll
    for (int q = 0; q < 8; ++q)
        fin[q] = (acc[q] + bf2f((unsigned short)own[q])) * dn + bias[s * 16 + p * 8 + q];
    // per-wave stats over both nodes (convergent cross-half shfl)
    float fs[8], fq[8];
    #pragma unroll
    for (int q = 0; q < 8; ++q) {
        float sq = fin[q] * fin[q];
        fs[q] = fin[q] + __shfl_xor(fin[q], 32);
        fq[q] = sq + __shfl_xor(sq, 32);
    }
    if (l < 2) {
        // output write (both halves, one lane per col-half)
        short8v ob;
        #pragma unroll
        for (int q = 0; q < 8; ++q) ob[q] = (short)f2bf(fin[q]);
        *(short8v*)(as_ + (size_t)s * SLN + (size_t)node * 16 + p * 8) = ob;
        if (h == 0) {
            #pragma unroll
            for (int q = 0; q < 8; ++q) {
                comb[w][p * 8 + q] = fs[q];
                comb[w][16 + p * 8 + q] = fq[q];
            }
        }
    }
    __syncthreads();
    int t = threadIdx.x;
    if (t < 32) {
        float v = comb[0][t] + comb[1][t] + comb[2][t] + comb[3][t];
        int copy = (blockIdx.x >> 3) & 63;
        if (t < 16) atomicAdd(&stats2[copy * 256 + s * 16 + t], v);
        else        atomicAdd(&stats2[copy * 256 + 128 + s * 16 + (t - 16)], v);
    }
}

// ------- CSR gather F=40 (64-padded linear rows): 8 groups x 8 lanes, conv. shfl --
__global__ __launch_bounds__(256) void k_gather40w(
    const unsigned short* __restrict__ hb, const float* __restrict__ dinv,
    const int* __restrict__ rowptr, const int* __restrict__ cecol,
    const float* __restrict__ bias, float* __restrict__ out) {
    const int w = threadIdx.x >> 6;
    const int lane = threadIdx.x & 63;
    const int g = lane >> 3;        // edge group 0..7
    const int q = lane & 7;         // cols q*8..q*8+7 (of 64-padded row)
    const int node = blockIdx.x * 4 + w;
    const int co = q * 8;

    float acc[8] = {};
    const int e0 = rowptr[node];
    const int ne = rowptr[node + 1] - e0;
    for (int cb = 0; cb < ne; cb += 64) {       // wave-uniform
        int idx = cecol[e0 + min(cb + lane, max(ne - 1, 0))];
        idx = min(max(idx, 0), NN - 1);
        const int clim = min(ne - cb, 64);
        const int nfull = clim >> 4;            // rounds of 16 (2 edges/group)
        int i = g;
        for (int r = 0; r < nfull; ++r, i += 16) {
            int s0 = __shfl(idx, i);
            int s1 = __shfl(idx, i + 8);
            short8v v0 = *(const short8v*)(hb + (size_t)s0 * 64 + co);
            short8v v1 = *(const short8v*)(hb + (size_t)s1 * 64 + co);
            #pragma unroll
            for (int j = 0; j < 8; ++j)
                acc[j] += bf2f((unsigned short)v0[j]) + bf2f((unsigned short)v1[j]);
        }
        if (clim & 15) {                        // wave-uniform partial round
            const int last = clim - 1;
            int j0 = i, j1 = i + 8;
            int s0 = __shfl(idx, min(j0, last));
            int s1 = __shfl(idx, min(j1, last));
            short8v v0 = *(const short8v*)(hb + (size_t)s0 * 64 + co);
            short8v v1 = *(const short8v*)(hb + (size_t)s1 * 64 + co);
            if (j0 < clim) {
                #pragma unroll
                for (int j = 0; j < 8; ++j) acc[j] += bf2f((unsigned short)v0[j]);
            }
            if (j1 < clim) {
                #pragma unroll
                for (int j = 0; j < 8; ++j) acc[j] += bf2f((unsigned short)v1[j]);
            }
        }
    }
    if (g == 0) {   // self-loop
        short8v v = *(const short8v*)(hb + (size_t)node * 64 + co);
        #pragma unroll
        for (int j = 0; j < 8; ++j)
            acc[j] += bf2f((unsigned short)v[j]);
    }
    #pragma unroll
    for (int j = 0; j < 8; ++j) {
        acc[j] += __shfl_xor(acc[j], 8);
        acc[j] += __shfl_xor(acc[j], 16);
        acc[j] += __shfl_xor(acc[j], 32);
    }
    if (g == 0 && co < 40) {        // q = 0..4 cover the 40 real cols
        float dn = dinv[node];
        float4 o0, o1;
        o0.x = acc[0] * dn + bias[co];
        o0.y = acc[1] * dn + bias[co + 1];
        o0.z = acc[2] * dn + bias[co + 2];
        o0.w = acc[3] * dn + bias[co + 3];
        o1.x = acc[4] * dn + bias[co + 4];
        o1.y = acc[5] * dn + bias[co + 5];
        o1.z = acc[6] * dn + bias[co + 6];
        o1.w = acc[7] * dn + bias[co + 7];
        float* op = out + (size_t)node * 40 + co;
        *(float4*)op = o0;
        *(float4*)(op + 4) = o1;
    }
}

// fold 64 stat copies + gamma/beta into scale/shift; re-zero stats2 for next use
__global__ void k_bnfinal2(float* __restrict__ stats2,
                           const float* __restrict__ gamma, const float* __restrict__ beta,
                           float* __restrict__ bnsc, float* __restrict__ bnsh) {
    int c = threadIdx.x;
    if (c >= 128) return;
    float s = 0.f, q = 0.f;
    for (int k = 0; k < 64; ++k) {
        s += stats2[k * 256 + c];
        q += stats2[k * 256 + 128 + c];
        stats2[k * 256 + c] = 0.f;
        stats2[k * 256 + 128 + c] = 0.f;
    }
    const float invn = 1.0f / (float)NN;
    float m = s * invn;
    float var = q * invn - m * m;
    float sc = gamma[c] * rsqrtf(var + EPS_BN);
    bnsc[c] = sc;
    bnsh[c] = beta[c] - m * sc;
}

extern "C" void kernel_launch(void* const* d_in, const int* in_sizes, int n_in,
                              void* d_out, int out_size, void* d_ws, size_t ws_size,
                              hipStream_t stream) {
    const float* x  = (const float*)d_in[0];
    const int*   ei = (const int*)d_in[1];
    const int*   src = ei;        // edge_index[0]
    const int*   dst = ei + NE;   // edge_index[1]
    const float* W0 = (const float*)d_in[2];
    const float* b0 = (const float*)d_in[3];
    const float* W1 = (const float*)d_in[4];
    const float* b1 = (const float*)d_in[5];
    const float* W2 = (const float*)d_in[6];
    const float* b2 = (const float*)d_in[7];
    const float* g0 = (const float*)d_in[8];
    const float* be0 = (const float*)d_in[9];
    const float* g1 = (const float*)d_in[10];
    const float* be1 = (const float*)d_in[11];
    float* out = (float*)d_out;

    // workspace layout (~75 MB)
    unsigned short* Hs   = (unsigned short*)d_ws;            // [8][NN][16] bf16 (gemm out)
    unsigned short* As   = Hs + (size_t)NN * 128;            // [8][NN][16] bf16 (gather out)
    unsigned short* H40  = Hs;                               // N*64 bf16 linear (aliases Hs)
    int2*           part = (int2*)(As + (size_t)NN * 128);   // NB*CAP int2
    int*            cecol = (int*)(part + (size_t)NB * CAP); // NE int
    float*          dinv = (float*)(cecol + NE);             // N
    float*          stats2 = dinv + NN;                      // 64*256
    float*          bnsc = stats2 + 64 * 256;                // 128
    float*          bnsh = bnsc + 128;                       // 128
    unsigned short* Wt0  = (unsigned short*)(bnsh + 128);    // 128*128 bf16
    unsigned short* Wt1  = Wt0 + 128 * 128;                  // 128*128 bf16
    unsigned short* Wt2  = Wt1 + 128 * 128;                  // 64*128 bf16
    int*            cnt  = (int*)(Wt2 + 64 * 128);           // N
    int*            fill = cnt + NN;                         // N
    int*            rowptr = fill + NN;                      // N+1
    int*            partial = rowptr + NN + 1;               // 512
    int*            cursors = partial + 512;                 // NB

    dim3 b256(256);
    int gN = (NN + 255) / 256;               // 391 (also covers stats2 64*256)
    int gPart = (NE + 4095) / 4096;          // 391
    int gBkt = NB * ((CAP + 4095) / 4096);   // 32*13 = 416

    // ---- CSR build (3-phase bucketed) ----
    k_init<<<gN, b256, 0, stream>>>(cnt, stats2, cursors);
    k_part<<<gPart, b256, 0, stream>>>(src, dst, cursors, part);
    k_hist32<<<gBkt, b256, 0, stream>>>(cursors, part, cnt);
    k_scan1<<<NP, b256, 0, stream>>>(cnt, rowptr, partial, dinv);
    k_scan2<<<1, 512, 0, stream>>>(partial);
    k_scan3<<<NP, b256, 0, stream>>>(rowptr, partial, fill);
    k_fill32<<<gBkt, b256, 0, stream>>>(cursors, part, fill, cecol);

    // ---- weight prep (fused) ----
    k_wconvall<<<160, b256, 0, stream>>>(W0, W1, W2, Wt0, Wt1, Wt2);

    int gGS = (NN / 8) * 8;   // 100000 blocks: slice = b&7, chunk = b>>3

    // ---- layer 0 ----
    k_gemm128_f<<<NN / 32, b256, 0, stream>>>(x, Wt0, Hs, dinv);
    k_gather128s<<<gGS, b256, 0, stream>>>(Hs, dinv, rowptr, cecol, b0, As, stats2);
    k_bnfinal2<<<1, 128, 0, stream>>>(stats2, g0, be0, bnsc, bnsh);

    // ---- layer 1 ----
    k_gemm128_b<<<NN / 32, b256, 0, stream>>>(As, Wt1, Hs, bnsc, bnsh, dinv);
    k_gather128s<<<gGS, b256, 0, stream>>>(Hs, dinv, rowptr, cecol, b1, As, stats2);
    k_bnfinal2<<<1, 128, 0, stream>>>(stats2, g1, be1, bnsc, bnsh);

    // ---- layer 2 (slice-major in, 64-col padded linear H40) ----
    k_gemm40_mfma<<<(NN + 63) / 64, b256, 0, stream>>>(As, Wt2, H40, bnsc, bnsh, dinv);
    k_gather40w<<<NN / 4, b256, 0, stream>>>(H40, dinv, rowptr, cecol, b2, out);
}

// Round 14
// 403.303 us; speedup vs baseline: 1.8603x; 1.8603x over previous
//
#include <hip/hip_runtime.h>

#define NN 100000
#define NE 1600000
#define EPS_BN 1e-5f
#define NP 391      // ceil(NN/256) scan partials
#define NB 32       // dst buckets
#define BW 3125     // NN / NB
#define CAP 53248   // bucket capacity (avg 50000), 13*4096

typedef __attribute__((ext_vector_type(8))) short short8v;
typedef __attribute__((ext_vector_type(4))) float f32x4;

__device__ __forceinline__ unsigned short f2bf(float f) {
    unsigned u = __float_as_uint(f);
    u += 0x7fff + ((u >> 16) & 1);          // RTNE
    return (unsigned short)(u >> 16);
}
__device__ __forceinline__ float bf2f(unsigned short h) {
    return __uint_as_float((unsigned)h << 16);
}

// ---------------- init: cnt zero, stats2 zero, cursors ----------------
__global__ void k_init(int* __restrict__ cnt, float* __restrict__ stats2,
                       int* __restrict__ cursors) {
    int i = blockIdx.x * 256 + threadIdx.x;
    if (i < NN) cnt[i] = 0;
    if (i < 64 * 256) stats2[i] = 0.f;
    if (i < NB) cursors[i] = i * CAP;
}

// Phase A: partition edges into 32 dst-range buckets, (dst,src) pairs.
__global__ __launch_bounds__(256) void k_part(const int* __restrict__ src,
                                              const int* __restrict__ dst,
                                              int* __restrict__ cursors,
                                              int2* __restrict__ part) {
    __shared__ int lh[4][NB];     // per-wave hist, then per-wave fill cursor
    __shared__ int lo[4][NB];     // per-wave base offset
    int t = threadIdx.x;
    int w = t >> 6;
    if (t < 128) lh[t >> 5][t & 31] = 0;
    __syncthreads();
    int base = blockIdx.x * 4096;
    int d[16], s[16], b[16];
    #pragma unroll 16
    for (int it = 0; it < 16; ++it) {
        int e = base + it * 256 + t;
        if (e < NE) {
            d[it] = dst[e];
            s[it] = src[e];
            b[it] = d[it] / BW;
            atomicAdd(&lh[w][b[it]], 1);
        } else b[it] = -1;
    }
    __syncthreads();
    if (t < NB) {
        int c0 = lh[0][t], c1 = lh[1][t], c2 = lh[2][t], c3 = lh[3][t];
        int tot = c0 + c1 + c2 + c3;
        int bb = atomicAdd(&cursors[t], tot);
        lo[0][t] = bb;
        lo[1][t] = bb + c0;
        lo[2][t] = bb + c0 + c1;
        lo[3][t] = bb + c0 + c1 + c2;
        lh[0][t] = 0; lh[1][t] = 0; lh[2][t] = 0; lh[3][t] = 0;
    }
    __syncthreads();
    #pragma unroll 16
    for (int it = 0; it < 16; ++it) {
        if (b[it] >= 0) {
            int pos = lo[w][b[it]] + atomicAdd(&lh[w][b[it]], 1);
            part[pos] = make_int2(d[it], s[it]);
        }
    }
}

// Phase B: per-bucket histogram; bucket b&31 stays on one XCD -> cnt slice L2-local.
__global__ void k_hist32(const int* __restrict__ cursors, const int2* __restrict__ part,
                         int* __restrict__ cnt) {
    int b = blockIdx.x & 31, chunk = blockIdx.x >> 5;
    int n = cursors[b] - b * CAP;
    const int2* p = part + (size_t)b * CAP;
    int i = chunk * 4096 + threadIdx.x;
    #pragma unroll 16
    for (int it = 0; it < 16; ++it, i += 256)
        if (i < n) atomicAdd(&cnt[p[i].x], 1);
}

__global__ __launch_bounds__(256) void k_scan1(const int* __restrict__ cnt,
                                               int* __restrict__ rowptr,
                                               int* __restrict__ partial,
                                               float* __restrict__ dinv) {
    __shared__ int sh[256];
    int i = blockIdx.x * 256 + threadIdx.x;
    int v = (i < NN) ? cnt[i] : 0;
    if (i < NN) dinv[i] = rsqrtf((float)(v + 1));         // +1 self-loop
    sh[threadIdx.x] = v;
    __syncthreads();
    for (int off = 1; off < 256; off <<= 1) {
        int t = (threadIdx.x >= off) ? sh[threadIdx.x - off] : 0;
        __syncthreads();
        sh[threadIdx.x] += t;
        __syncthreads();
    }
    if (i < NN) rowptr[i] = sh[threadIdx.x] - v;           // exclusive
    if (threadIdx.x == 255) partial[blockIdx.x] = sh[255]; // block total
}

__global__ __launch_bounds__(512) void k_scan2(int* __restrict__ partial) {
    __shared__ int sh[512];
    int tid = threadIdx.x;
    int v = (tid < NP) ? partial[tid] : 0;
    sh[tid] = v;
    __syncthreads();
    for (int off = 1; off < 512; off <<= 1) {
        int t = (tid >= off) ? sh[tid - off] : 0;
        __syncthreads();
        sh[tid] += t;
        __syncthreads();
    }
    if (tid < NP) partial[tid] = sh[tid] - v;              // exclusive
}

__global__ void k_scan3(int* __restrict__ rowptr, const int* __restrict__ partial,
                        int* __restrict__ fill) {
    int i = blockIdx.x * 256 + threadIdx.x;
    if (i < NN) {
        int v = rowptr[i] + partial[blockIdx.x];
        rowptr[i] = v;
        fill[i] = v;                                       // fill cursor = row start
    }
    if (i == 0) rowptr[NN] = NE;
}

// Phase C: per-bucket CSR fill (col only); cecol slice ~200KB stays in XCD L2.
__global__ void k_fill32(const int* __restrict__ cursors, const int2* __restrict__ part,
                         int* __restrict__ fill, int* __restrict__ cecol) {
    int b = blockIdx.x & 31, chunk = blockIdx.x >> 5;
    int n = cursors[b] - b * CAP;
    const int2* p = part + (size_t)b * CAP;
    int i = chunk * 4096 + threadIdx.x;
    #pragma unroll 16
    for (int it = 0; it < 16; ++it, i += 256) {
        if (i < n) {
            int2 e = p[i];
            int pos = atomicAdd(&fill[e.x], 1);
            cecol[pos] = e.y;
        }
    }
}

// ---------------- fused weight convert: W0,W1 -> Wt[c][k]; W2 -> [64][128] padded --
__global__ void k_wconvall(const float* __restrict__ W0, const float* __restrict__ W1,
                           const float* __restrict__ W2,
                           unsigned short* __restrict__ Wt0,
                           unsigned short* __restrict__ Wt1,
                           unsigned short* __restrict__ Wt2) {
    int idx = blockIdx.x * 256 + threadIdx.x;
    if (idx < 16384) {
        int k = idx >> 7, c = idx & 127;
        Wt0[c * 128 + k] = f2bf(W0[idx]);
    } else if (idx < 32768) {
        int j = idx - 16384;
        int k = j >> 7, c = j & 127;
        Wt1[c * 128 + k] = f2bf(W1[j]);
    } else if (idx < 32768 + 8192) {
        int j = idx - 32768;
        int c = j >> 7, k = j & 127;
        Wt2[j] = (c < 40) ? f2bf(W2[k * 40 + c]) : (unsigned short)0;
    }
}

#define XPAD 136   // LDS row stride in ushorts: 272B = 68 words, 68%32=4 -> 2-way max

// ---------------- MFMA GEMM (layer 0): f32 input, out rows pre-scaled by dinv ------
__global__ __launch_bounds__(256) void k_gemm128_f(
    const float* __restrict__ in, const unsigned short* __restrict__ Wt,
    unsigned short* __restrict__ outb, const float* __restrict__ dinv) {
    __shared__ unsigned short xs[32 * XPAD];
    __shared__ float dsv[32];
    const int tid = threadIdx.x;
    const int row0 = blockIdx.x * 32;
    if (tid < 32) dsv[tid] = dinv[row0 + tid];
    for (int i = tid; i < 1024; i += 256) {
        float4 v = ((const float4*)(in + (size_t)row0 * 128))[i];
        int c4 = (i & 31) * 4;
        ushort4 b;
        b.x = f2bf(v.x); b.y = f2bf(v.y); b.z = f2bf(v.z); b.w = f2bf(v.w);
        *(ushort4*)&xs[(i >> 5) * XPAD + c4] = b;
    }
    __syncthreads();

    const int w = tid >> 6;
    const int L = tid & 63;
    const int l15 = L & 15;
    const int l4 = L >> 4;
    f32x4 acc[2][2] = {{{0.f, 0.f, 0.f, 0.f}, {0.f, 0.f, 0.f, 0.f}},
                       {{0.f, 0.f, 0.f, 0.f}, {0.f, 0.f, 0.f, 0.f}}};
    const unsigned short* Wb0 = Wt + (size_t)(w * 32 + l15) * 128;
    const unsigned short* Wb1 = Wt + (size_t)(w * 32 + 16 + l15) * 128;
    #pragma unroll
    for (int kk = 0; kk < 4; ++kk) {
        int k0 = kk * 32 + l4 * 8;
        short8v a0 = *(const short8v*)&xs[l15 * XPAD + k0];
        short8v a1 = *(const short8v*)&xs[(16 + l15) * XPAD + k0];
        short8v b0 = *(const short8v*)&Wb0[k0];
        short8v b1 = *(const short8v*)&Wb1[k0];
        acc[0][0] = __builtin_amdgcn_mfma_f32_16x16x32_bf16(a0, b0, acc[0][0], 0, 0, 0);
        acc[0][1] = __builtin_amdgcn_mfma_f32_16x16x32_bf16(a0, b1, acc[0][1], 0, 0, 0);
        acc[1][0] = __builtin_amdgcn_mfma_f32_16x16x32_bf16(a1, b0, acc[1][0], 0, 0, 0);
        acc[1][1] = __builtin_amdgcn_mfma_f32_16x16x32_bf16(a1, b1, acc[1][1], 0, 0, 0);
    }
    #pragma unroll
    for (int h = 0; h < 2; ++h)
        #pragma unroll
        for (int c = 0; c < 2; ++c) {
            int colg = w * 32 + c * 16 + l15;
            #pragma unroll
            for (int r = 0; r < 4; ++r) {
                int rl = h * 16 + l4 * 4 + r;
                outb[(size_t)(row0 + rl) * 128 + colg] = f2bf(acc[h][c][r] * dsv[rl]);
            }
        }
}

// ---------------- MFMA GEMM (layer 1): bf16 input + BN+ReLU, dinv-scaled out ------
__global__ __launch_bounds__(256) void k_gemm128_b(
    const unsigned short* __restrict__ inb, const unsigned short* __restrict__ Wt,
    unsigned short* __restrict__ outb,
    const float* __restrict__ bnsc, const float* __restrict__ bnsh,
    const float* __restrict__ dinv) {
    __shared__ unsigned short xs[32 * XPAD];
    __shared__ float dsv[32];
    const int tid = threadIdx.x;
    const int row0 = blockIdx.x * 32;
    if (tid < 32) dsv[tid] = dinv[row0 + tid];
    const unsigned short* inp = inb + (size_t)row0 * 128;
    for (int i = tid; i < 512; i += 256) {
        int r = i >> 4, c8 = (i & 15) * 8;
        short8v u = *(const short8v*)(inp + r * 128 + c8);
        short8v o;
        #pragma unroll
        for (int j = 0; j < 8; ++j) {
            float v = bf2f((unsigned short)u[j]);
            v = fmaxf(v * bnsc[c8 + j] + bnsh[c8 + j], 0.f);
            o[j] = (short)f2bf(v);
        }
        *(short8v*)&xs[r * XPAD + c8] = o;
    }
    __syncthreads();

    const int w = tid >> 6;
    const int L = tid & 63;
    const int l15 = L & 15;
    const int l4 = L >> 4;
    f32x4 acc[2][2] = {{{0.f, 0.f, 0.f, 0.f}, {0.f, 0.f, 0.f, 0.f}},
                       {{0.f, 0.f, 0.f, 0.f}, {0.f, 0.f, 0.f, 0.f}}};
    const unsigned short* Wb0 = Wt + (size_t)(w * 32 + l15) * 128;
    const unsigned short* Wb1 = Wt + (size_t)(w * 32 + 16 + l15) * 128;
    #pragma unroll
    for (int kk = 0; kk < 4; ++kk) {
        int k0 = kk * 32 + l4 * 8;
        short8v a0 = *(const short8v*)&xs[l15 * XPAD + k0];
        short8v a1 = *(const short8v*)&xs[(16 + l15) * XPAD + k0];
        short8v b0 = *(const short8v*)&Wb0[k0];
        short8v b1 = *(const short8v*)&Wb1[k0];
        acc[0][0] = __builtin_amdgcn_mfma_f32_16x16x32_bf16(a0, b0, acc[0][0], 0, 0, 0);
        acc[0][1] = __builtin_amdgcn_mfma_f32_16x16x32_bf16(a0, b1, acc[0][1], 0, 0, 0);
        acc[1][0] = __builtin_amdgcn_mfma_f32_16x16x32_bf16(a1, b0, acc[1][0], 0, 0, 0);
        acc[1][1] = __builtin_amdgcn_mfma_f32_16x16x32_bf16(a1, b1, acc[1][1], 0, 0, 0);
    }
    #pragma unroll
    for (int h = 0; h < 2; ++h)
        #pragma unroll
        for (int c = 0; c < 2; ++c) {
            int colg = w * 32 + c * 16 + l15;
            #pragma unroll
            for (int r = 0; r < 4; ++r) {
                int rl = h * 16 + l4 * 4 + r;
                outb[(size_t)(row0 + rl) * 128 + colg] = f2bf(acc[h][c][r] * dsv[rl]);
            }
        }
}

// ------- MFMA GEMM (layer 2): bf16 in + BN+ReLU, out[N,64] bf16 (cols 40+ = 0) ----
__global__ __launch_bounds__(256) void k_gemm40_mfma(
    const unsigned short* __restrict__ inb, const unsigned short* __restrict__ Wt,
    unsigned short* __restrict__ outb,
    const float* __restrict__ bnsc, const float* __restrict__ bnsh,
    const float* __restrict__ dinv) {
    __shared__ unsigned short xs[64 * XPAD];
    __shared__ float dsv[64];
    const int tid = threadIdx.x;
    const int row0 = blockIdx.x * 64;
    if (tid < 64) dsv[tid] = (row0 + tid < NN) ? dinv[row0 + tid] : 0.f;
    for (int i = tid; i < 1024; i += 256) {
        int r = i >> 4, c8 = (i & 15) * 8;
        short8v u = {0, 0, 0, 0, 0, 0, 0, 0};
        if (row0 + r < NN) u = *(const short8v*)(inb + (size_t)(row0 + r) * 128 + c8);
        short8v o;
        #pragma unroll
        for (int j = 0; j < 8; ++j) {
            float v = bf2f((unsigned short)u[j]);
            v = fmaxf(v * bnsc[c8 + j] + bnsh[c8 + j], 0.f);
            o[j] = (short)f2bf(v);
        }
        *(short8v*)&xs[r * XPAD + c8] = o;
    }
    __syncthreads();

    const int w = tid >> 6;
    const int L = tid & 63;
    const int l15 = L & 15;
    const int l4 = L >> 4;
    f32x4 acc[4] = {{0.f, 0.f, 0.f, 0.f}, {0.f, 0.f, 0.f, 0.f},
                    {0.f, 0.f, 0.f, 0.f}, {0.f, 0.f, 0.f, 0.f}};
    #pragma unroll
    for (int kk = 0; kk < 4; ++kk) {
        int k0 = kk * 32 + l4 * 8;
        short8v a = *(const short8v*)&xs[(w * 16 + l15) * XPAD + k0];
        #pragma unroll
        for (int cgi = 0; cgi < 4; ++cgi) {
            short8v b = *(const short8v*)&Wt[(size_t)(cgi * 16 + l15) * 128 + k0];
            acc[cgi] = __builtin_amdgcn_mfma_f32_16x16x32_bf16(a, b, acc[cgi], 0, 0, 0);
        }
    }
    #pragma unroll
    for (int cgi = 0; cgi < 4; ++cgi) {
        int colg = cgi * 16 + l15;
        #pragma unroll
        for (int r = 0; r < 4; ++r) {
            int rl = w * 16 + l4 * 4 + r;
            if (row0 + rl < NN)
                outb[(size_t)(row0 + rl) * 64 + colg] = f2bf(acc[cgi][r] * dsv[rl]);
        }
    }
}

// ---------------- CSR gather F=128: convergent shfl-idx, 16B row loads -----------
__global__ __launch_bounds__(256) void k_gather128c(
    const unsigned short* __restrict__ hb, const float* __restrict__ dinv,
    const int* __restrict__ rowptr, const int* __restrict__ cecol,
    const float* __restrict__ bias, unsigned short* __restrict__ aggb,
    float* __restrict__ stats2) {
    __shared__ float comb[4][256];
    const int w = threadIdx.x >> 6;
    const int lane = threadIdx.x & 63;
    const int g = lane >> 4;        // edge group 0..3
    const int q = lane & 15;        // column block: cols q*8..q*8+7
    const int node = blockIdx.x * 4 + w;   // NN % 4 == 0, grid exact
    const int co = q * 8;

    float acc[8] = {};
    const int e0 = rowptr[node];
    const int ne = rowptr[node + 1] - e0;       // wave-uniform
    for (int cb = 0; cb < ne; cb += 64) {       // wave-uniform chunk loop
        int idx = cecol[e0 + min(cb + lane, ne - 1)];   // coalesced, 64 idx/wave
        const int clim = min(ne - cb, 64);      // wave-uniform
        const int nfull = clim >> 4;            // full rounds of 16 edges
        int i = g;
        for (int r = 0; r < nfull; ++r, i += 16) {   // uniform trip count
            int s0 = __shfl(idx, i);
            int s1 = __shfl(idx, i + 4);
            int s2 = __shfl(idx, i + 8);
            int s3 = __shfl(idx, i + 12);
            short8v v0 = *(const short8v*)(hb + (size_t)s0 * 128 + co);
            short8v v1 = *(const short8v*)(hb + (size_t)s1 * 128 + co);
            short8v v2 = *(const short8v*)(hb + (size_t)s2 * 128 + co);
            short8v v3 = *(const short8v*)(hb + (size_t)s3 * 128 + co);
            #pragma unroll
            for (int j = 0; j < 8; ++j)
                acc[j] += (bf2f((unsigned short)v0[j]) + bf2f((unsigned short)v1[j]))
                        + (bf2f((unsigned short)v2[j]) + bf2f((unsigned short)v3[j]));
        }
        if (clim & 15) {                        // wave-uniform partial round
            const int last = clim - 1;
            int j0 = i, j1 = i + 4, j2 = i + 8, j3 = i + 12;
            int s0 = __shfl(idx, min(j0, last));     // convergent shfl, clamped
            int s1 = __shfl(idx, min(j1, last));
            int s2 = __shfl(idx, min(j2, last));
            int s3 = __shfl(idx, min(j3, last));
            short8v v0 = *(const short8v*)(hb + (size_t)s0 * 128 + co);
            short8v v1 = *(const short8v*)(hb + (size_t)s1 * 128 + co);
            short8v v2 = *(const short8v*)(hb + (size_t)s2 * 128 + co);
            short8v v3 = *(const short8v*)(hb + (size_t)s3 * 128 + co);
            if (j0 < clim) {
                #pragma unroll
                for (int j = 0; j < 8; ++j) acc[j] += bf2f((unsigned short)v0[j]);
            }
            if (j1 < clim) {
                #pragma unroll
                for (int j = 0; j < 8; ++j) acc[j] += bf2f((unsigned short)v1[j]);
            }
            if (j2 < clim) {
                #pragma unroll
                for (int j = 0; j < 8; ++j) acc[j] += bf2f((unsigned short)v2[j]);
            }
            if (j3 < clim) {
                #pragma unroll
                for (int j = 0; j < 8; ++j) acc[j] += bf2f((unsigned short)v3[j]);
            }
        }
    }
    if (g == 0) {   // self-loop row, added once (no shfl inside)
        short8v v = *(const short8v*)(hb + (size_t)node * 128 + co);
        #pragma unroll
        for (int j = 0; j < 8; ++j)
            acc[j] += bf2f((unsigned short)v[j]);
    }
    // cross-group butterfly (convergent): lanes {q, q+16, q+32, q+48} sum
    #pragma unroll
    for (int j = 0; j < 8; ++j) {
        acc[j] += __shfl_xor(acc[j], 16);
        acc[j] += __shfl_xor(acc[j], 32);
    }
    float dn = dinv[node];
    float fin[8];
    #pragma unroll
    for (int j = 0; j < 8; ++j)
        fin[j] = acc[j] * dn + bias[co + j];
    if (g == 0) {
        short8v ob;
        #pragma unroll
        for (int j = 0; j < 8; ++j) ob[j] = (short)f2bf(fin[j]);
        *(short8v*)(aggb + (size_t)node * 128 + co) = ob;
        float4 f0 = {fin[0], fin[1], fin[2], fin[3]};
        float4 f1 = {fin[4], fin[5], fin[6], fin[7]};
        *(float4*)&comb[w][co] = f0;
        *(float4*)&comb[w][co + 4] = f1;
    }
    if (g == 1) {
        float4 f0 = {fin[0] * fin[0], fin[1] * fin[1], fin[2] * fin[2], fin[3] * fin[3]};
        float4 f1 = {fin[4] * fin[4], fin[5] * fin[5], fin[6] * fin[6], fin[7] * fin[7]};
        *(float4*)&comb[w][128 + co] = f0;
        *(float4*)&comb[w][132 + co] = f1;
    }
    __syncthreads();
    int t = threadIdx.x;
    float v = comb[0][t] + comb[1][t] + comb[2][t] + comb[3][t];
    atomicAdd(&stats2[(blockIdx.x & 63) * 256 + t], v);
}

// ------- CSR gather F=40 (64-padded rows): 8 groups x 8 lanes, convergent shfl ----
__global__ __launch_bounds__(256) void k_gather40w(
    const unsigned short* __restrict__ hb, const float* __restrict__ dinv,
    const int* __restrict__ rowptr, const int* __restrict__ cecol,
    const float* __restrict__ bias, float* __restrict__ out) {
    const int w = threadIdx.x >> 6;
    const int lane = threadIdx.x & 63;
    const int g = lane >> 3;        // edge group 0..7
    const int q = lane & 7;         // cols q*8..q*8+7 (of 64-padded row)
    const int node = blockIdx.x * 4 + w;
    const int co = q * 8;

    float acc[8] = {};
    const int e0 = rowptr[node];
    const int ne = rowptr[node + 1] - e0;
    for (int cb = 0; cb < ne; cb += 64) {       // wave-uniform
        int idx = cecol[e0 + min(cb + lane, ne - 1)];
        const int clim = min(ne - cb, 64);
        const int nfull = clim >> 4;            // rounds of 16 (2 edges/group)
        int i = g;
        for (int r = 0; r < nfull; ++r, i += 16) {
            int s0 = __shfl(idx, i);
            int s1 = __shfl(idx, i + 8);
            short8v v0 = *(const short8v*)(hb + (size_t)s0 * 64 + co);
            short8v v1 = *(const short8v*)(hb + (size_t)s1 * 64 + co);
            #pragma unroll
            for (int j = 0; j < 8; ++j)
                acc[j] += bf2f((unsigned short)v0[j]) + bf2f((unsigned short)v1[j]);
        }
        if (clim & 15) {                        // wave-uniform partial round
            const int last = clim - 1;
            int j0 = i, j1 = i + 8;
            int s0 = __shfl(idx, min(j0, last));
            int s1 = __shfl(idx, min(j1, last));
            short8v v0 = *(const short8v*)(hb + (size_t)s0 * 64 + co);
            short8v v1 = *(const short8v*)(hb + (size_t)s1 * 64 + co);
            if (j0 < clim) {
                #pragma unroll
                for (int j = 0; j < 8; ++j) acc[j] += bf2f((unsigned short)v0[j]);
            }
            if (j1 < clim) {
                #pragma unroll
                for (int j = 0; j < 8; ++j) acc[j] += bf2f((unsigned short)v1[j]);
            }
        }
    }
    if (g == 0) {   // self-loop
        short8v v = *(const short8v*)(hb + (size_t)node * 64 + co);
        #pragma unroll
        for (int j = 0; j < 8; ++j)
            acc[j] += bf2f((unsigned short)v[j]);
    }
    #pragma unroll
    for (int j = 0; j < 8; ++j) {
        acc[j] += __shfl_xor(acc[j], 8);
        acc[j] += __shfl_xor(acc[j], 16);
        acc[j] += __shfl_xor(acc[j], 32);
    }
    if (g == 0 && co < 40) {        // q = 0..4 cover the 40 real cols
        float dn = dinv[node];
        float4 o0, o1;
        o0.x = acc[0] * dn + bias[co];
        o0.y = acc[1] * dn + bias[co + 1];
        o0.z = acc[2] * dn + bias[co + 2];
        o0.w = acc[3] * dn + bias[co + 3];
        o1.x = acc[4] * dn + bias[co + 4];
        o1.y = acc[5] * dn + bias[co + 5];
        o1.z = acc[6] * dn + bias[co + 6];
        o1.w = acc[7] * dn + bias[co + 7];
        float* op = out + (size_t)node * 40 + co;
        *(float4*)op = o0;
        *(float4*)(op + 4) = o1;
    }
}

// fold 64 stat copies + gamma/beta into scale/shift; re-zero stats2 for next use
__global__ void k_bnfinal2(float* __restrict__ stats2,
                           const float* __restrict__ gamma, const float* __restrict__ beta,
                           float* __restrict__ bnsc, float* __restrict__ bnsh) {
    int c = threadIdx.x;
    if (c >= 128) return;
    float s = 0.f, q = 0.f;
    for (int k = 0; k < 64; ++k) {
        s += stats2[k * 256 + c];
        q += stats2[k * 256 + 128 + c];
        stats2[k * 256 + c] = 0.f;
        stats2[k * 256 + 128 + c] = 0.f;
    }
    const float invn = 1.0f / (float)NN;
    float m = s * invn;
    float var = q * invn - m * m;
    float sc = gamma[c] * rsqrtf(var + EPS_BN);
    bnsc[c] = sc;
    bnsh[c] = beta[c] - m * sc;
}

extern "C" void kernel_launch(void* const* d_in, const int* in_sizes, int n_in,
                              void* d_out, int out_size, void* d_ws, size_t ws_size,
                              hipStream_t stream) {
    const float* x  = (const float*)d_in[0];
    const int*   ei = (const int*)d_in[1];
    const int*   src = ei;        // edge_index[0]
    const int*   dst = ei + NE;   // edge_index[1]
    const float* W0 = (const float*)d_in[2];
    const float* b0 = (const float*)d_in[3];
    const float* W1 = (const float*)d_in[4];
    const float* b1 = (const float*)d_in[5];
    const float* W2 = (const float*)d_in[6];
    const float* b2 = (const float*)d_in[7];
    const float* g0 = (const float*)d_in[8];
    const float* be0 = (const float*)d_in[9];
    const float* g1 = (const float*)d_in[10];
    const float* be1 = (const float*)d_in[11];
    float* out = (float*)d_out;

    // workspace layout (~75 MB)
    unsigned short* Hb   = (unsigned short*)d_ws;            // N*128 bf16 (gemm out, dinv-scaled)
    unsigned short* Ab   = Hb + (size_t)NN * 128;            // N*128 bf16 (gather out)
    unsigned short* H40  = Hb;                               // N*64 bf16 (aliases Hb)
    int2*           part = (int2*)(Ab + (size_t)NN * 128);   // NB*CAP int2
    int*            cecol = (int*)(part + (size_t)NB * CAP); // NE int
    float*          dinv = (float*)(cecol + NE);             // N
    float*          stats2 = dinv + NN;                      // 64*256
    float*          bnsc = stats2 + 64 * 256;                // 128
    float*          bnsh = bnsc + 128;                       // 128
    unsigned short* Wt0  = (unsigned short*)(bnsh + 128);    // 128*128 bf16
    unsigned short* Wt1  = Wt0 + 128 * 128;                  // 128*128 bf16
    unsigned short* Wt2  = Wt1 + 128 * 128;                  // 64*128 bf16
    int*            cnt  = (int*)(Wt2 + 64 * 128);           // N
    int*            fill = cnt + NN;                         // N
    int*            rowptr = fill + NN;                      // N+1
    int*            partial = rowptr + NN + 1;               // 512
    int*            cursors = partial + 512;                 // NB

    dim3 b256(256);
    int gN = (NN + 255) / 256;               // 391 (also covers stats2 64*256)
    int gPart = (NE + 4095) / 4096;          // 391
    int gBkt = NB * ((CAP + 4095) / 4096);   // 32*13 = 416

    // ---- CSR build (3-phase bucketed) ----
    k_init<<<gN, b256, 0, stream>>>(cnt, stats2, cursors);
    k_part<<<gPart, b256, 0, stream>>>(src, dst, cursors, part);
    k_hist32<<<gBkt, b256, 0, stream>>>(cursors, part, cnt);
    k_scan1<<<NP, b256, 0, stream>>>(cnt, rowptr, partial, dinv);
    k_scan2<<<1, 512, 0, stream>>>(partial);
    k_scan3<<<NP, b256, 0, stream>>>(rowptr, partial, fill);
    k_fill32<<<gBkt, b256, 0, stream>>>(cursors, part, fill, cecol);

    // ---- weight prep (fused) ----
    k_wconvall<<<160, b256, 0, stream>>>(W0, W1, W2, Wt0, Wt1, Wt2);

    int gG = NN / 4;   // 25000, exact

    // ---- layer 0 ----
    k_gemm128_f<<<NN / 32, b256, 0, stream>>>(x, Wt0, Hb, dinv);
    k_gather128c<<<gG, b256, 0, stream>>>(Hb, dinv, rowptr, cecol, b0, Ab, stats2);
    k_bnfinal2<<<1, 128, 0, stream>>>(stats2, g0, be0, bnsc, bnsh);

    // ---- layer 1 ----
    k_gemm128_b<<<NN / 32, b256, 0, stream>>>(Ab, Wt1, Hb, bnsc, bnsh, dinv);
    k_gather128c<<<gG, b256, 0, stream>>>(Hb, dinv, rowptr, cecol, b1, Ab, stats2);
    k_bnfinal2<<<1, 128, 0, stream>>>(stats2, g1, be1, bnsc, bnsh);

    // ---- layer 2 (64-col padded H40) ----
    k_gemm40_mfma<<<(NN + 63) / 64, b256, 0, stream>>>(Ab, Wt2, H40, bnsc, bnsh, dinv);
    k_gather40w<<<NN / 4, b256, 0, stream>>>(H40, dinv, rowptr, cecol, b2, out);
}

// Round 15
// 385.496 us; speedup vs baseline: 1.9462x; 1.0462x over previous
//
#include <hip/hip_runtime.h>

#define NN 100000
#define NE 1600000
#define EPS_BN 1e-5f
#define NB 32       // dst buckets
#define BW 3125     // NN / NB
#define CAP 53248   // bucket capacity (avg 50000, +14 sigma)
#define SEG 13      // ceil(BW/256) scan segment per thread

typedef __attribute__((ext_vector_type(8))) short short8v;
typedef __attribute__((ext_vector_type(4))) float f32x4;

__device__ __forceinline__ unsigned short f2bf(float f) {
    unsigned u = __float_as_uint(f);
    u += 0x7fff + ((u >> 16) & 1);          // RTNE
    return (unsigned short)(u >> 16);
}
__device__ __forceinline__ float bf2f(unsigned short h) {
    return __uint_as_float((unsigned)h << 16);
}

// ---------------- init: stats2 zero, cursors ----------------
__global__ void k_init(float* __restrict__ stats2, int* __restrict__ cursors) {
    int i = blockIdx.x * 256 + threadIdx.x;
    if (i < 64 * 256) stats2[i] = 0.f;
    if (i < NB) cursors[i] = i * CAP;
}

// Phase A: partition edges into 32 dst-range buckets; pack (dloc<<17)|src.
__global__ __launch_bounds__(256) void k_part(const int* __restrict__ src,
                                              const int* __restrict__ dst,
                                              int* __restrict__ cursors,
                                              int* __restrict__ part) {
    __shared__ int lh[4][NB];     // per-wave hist, then per-wave fill cursor
    __shared__ int lo[4][NB];     // per-wave base offset
    int t = threadIdx.x;
    int w = t >> 6;
    if (t < 128) lh[t >> 5][t & 31] = 0;
    __syncthreads();
    int base = blockIdx.x * 4096;
    int pk[16], b[16];
    #pragma unroll 16
    for (int it = 0; it < 16; ++it) {
        int e = base + it * 256 + t;
        if (e < NE) {
            int d = dst[e];
            int s = src[e];
            b[it] = d / BW;
            pk[it] = ((d - b[it] * BW) << 17) | s;
            atomicAdd(&lh[w][b[it]], 1);
        } else b[it] = -1;
    }
    __syncthreads();
    if (t < NB) {
        int c0 = lh[0][t], c1 = lh[1][t], c2 = lh[2][t], c3 = lh[3][t];
        int tot = c0 + c1 + c2 + c3;
        int bb = atomicAdd(&cursors[t], tot);
        lo[0][t] = bb;
        lo[1][t] = bb + c0;
        lo[2][t] = bb + c0 + c1;
        lo[3][t] = bb + c0 + c1 + c2;
        lh[0][t] = 0; lh[1][t] = 0; lh[2][t] = 0; lh[3][t] = 0;
    }
    __syncthreads();
    #pragma unroll 16
    for (int it = 0; it < 16; ++it) {
        if (b[it] >= 0) {
            int pos = lo[w][b[it]] + atomicAdd(&lh[w][b[it]], 1);
            part[pos] = pk[it];
        }
    }
}

// Phase B+C fused: one block per bucket. LDS histogram -> LDS exclusive scan
// (rowptr + dinv slice) -> LDS-cursor CSR fill of contiguous cecol slice.
__global__ __launch_bounds__(256) void k_bucket(const int* __restrict__ cursors,
                                                const int* __restrict__ part,
                                                int* __restrict__ rowptr,
                                                float* __restrict__ dinv,
                                                int* __restrict__ cecol) {
    __shared__ int hist[BW];      // 12.5 KB
    __shared__ int tsum[256];
    const int b = blockIdx.x;
    const int t = threadIdx.x;
    const int n = cursors[b] - b * CAP;
    const int* p = part + (size_t)b * CAP;
    for (int i = t; i < BW; i += 256) hist[i] = 0;
    __syncthreads();
    for (int i = t; i < n; i += 256)
        atomicAdd(&hist[p[i] >> 17], 1);
    __syncthreads();
    // per-thread segment sum
    const int s0 = t * SEG;
    const int s1 = min(s0 + SEG, BW);
    int run = 0;
    for (int i = s0; i < s1; ++i) run += hist[i];
    tsum[t] = run;
    __syncthreads();
    // Hillis-Steele block scan (inclusive)
    for (int off = 1; off < 256; off <<= 1) {
        int v = (t >= off) ? tsum[t - off] : 0;
        __syncthreads();
        tsum[t] += v;
        __syncthreads();
    }
    // bucket base = total edges in buckets < b
    int base = 0;
    for (int k = 0; k < b; ++k) base += cursors[k] - k * CAP;
    int pref = base + ((t > 0) ? tsum[t - 1] : 0);
    // rewrite hist -> exclusive prefix (fill cursors); emit rowptr + dinv
    for (int i = s0; i < s1; ++i) {
        int c = hist[i];
        hist[i] = pref;
        rowptr[b * BW + i] = pref;
        dinv[b * BW + i] = rsqrtf((float)(c + 1));   // +1 self-loop
        pref += c;
    }
    if (b == NB - 1 && t == 0) rowptr[NN] = NE;
    __syncthreads();
    // fill
    for (int i = t; i < n; i += 256) {
        int u = p[i];
        int pos = atomicAdd(&hist[u >> 17], 1);
        cecol[pos] = u & 0x1FFFF;
    }
}

// ---------------- fused weight convert: W0,W1 -> Wt[c][k]; W2 -> [64][128] padded --
__global__ void k_wconvall(const float* __restrict__ W0, const float* __restrict__ W1,
                           const float* __restrict__ W2,
                           unsigned short* __restrict__ Wt0,
                           unsigned short* __restrict__ Wt1,
                           unsigned short* __restrict__ Wt2) {
    int idx = blockIdx.x * 256 + threadIdx.x;
    if (idx < 16384) {
        int k = idx >> 7, c = idx & 127;
        Wt0[c * 128 + k] = f2bf(W0[idx]);
    } else if (idx < 32768) {
        int j = idx - 16384;
        int k = j >> 7, c = j & 127;
        Wt1[c * 128 + k] = f2bf(W1[j]);
    } else if (idx < 32768 + 8192) {
        int j = idx - 32768;
        int c = j >> 7, k = j & 127;
        Wt2[j] = (c < 40) ? f2bf(W2[k * 40 + c]) : (unsigned short)0;
    }
}

#define XPAD 136   // LDS row stride in ushorts: 272B = 68 words, 68%32=4 -> 2-way max

// ---------------- MFMA GEMM (layer 0): f32 input, out rows pre-scaled by dinv ------
__global__ __launch_bounds__(256) void k_gemm128_f(
    const float* __restrict__ in, const unsigned short* __restrict__ Wt,
    unsigned short* __restrict__ outb, const float* __restrict__ dinv) {
    __shared__ unsigned short xs[32 * XPAD];
    __shared__ float dsv[32];
    const int tid = threadIdx.x;
    const int row0 = blockIdx.x * 32;
    if (tid < 32) dsv[tid] = dinv[row0 + tid];
    for (int i = tid; i < 1024; i += 256) {
        float4 v = ((const float4*)(in + (size_t)row0 * 128))[i];
        int c4 = (i & 31) * 4;
        ushort4 b;
        b.x = f2bf(v.x); b.y = f2bf(v.y); b.z = f2bf(v.z); b.w = f2bf(v.w);
        *(ushort4*)&xs[(i >> 5) * XPAD + c4] = b;
    }
    __syncthreads();

    const int w = tid >> 6;
    const int L = tid & 63;
    const int l15 = L & 15;
    const int l4 = L >> 4;
    f32x4 acc[2][2] = {{{0.f, 0.f, 0.f, 0.f}, {0.f, 0.f, 0.f, 0.f}},
                       {{0.f, 0.f, 0.f, 0.f}, {0.f, 0.f, 0.f, 0.f}}};
    const unsigned short* Wb0 = Wt + (size_t)(w * 32 + l15) * 128;
    const unsigned short* Wb1 = Wt + (size_t)(w * 32 + 16 + l15) * 128;
    #pragma unroll
    for (int kk = 0; kk < 4; ++kk) {
        int k0 = kk * 32 + l4 * 8;
        short8v a0 = *(const short8v*)&xs[l15 * XPAD + k0];
        short8v a1 = *(const short8v*)&xs[(16 + l15) * XPAD + k0];
        short8v b0 = *(const short8v*)&Wb0[k0];
        short8v b1 = *(const short8v*)&Wb1[k0];
        acc[0][0] = __builtin_amdgcn_mfma_f32_16x16x32_bf16(a0, b0, acc[0][0], 0, 0, 0);
        acc[0][1] = __builtin_amdgcn_mfma_f32_16x16x32_bf16(a0, b1, acc[0][1], 0, 0, 0);
        acc[1][0] = __builtin_amdgcn_mfma_f32_16x16x32_bf16(a1, b0, acc[1][0], 0, 0, 0);
        acc[1][1] = __builtin_amdgcn_mfma_f32_16x16x32_bf16(a1, b1, acc[1][1], 0, 0, 0);
    }
    #pragma unroll
    for (int h = 0; h < 2; ++h)
        #pragma unroll
        for (int c = 0; c < 2; ++c) {
            int colg = w * 32 + c * 16 + l15;
            #pragma unroll
            for (int r = 0; r < 4; ++r) {
                int rl = h * 16 + l4 * 4 + r;
                outb[(size_t)(row0 + rl) * 128 + colg] = f2bf(acc[h][c][r] * dsv[rl]);
            }
        }
}

// ---------------- MFMA GEMM (layer 1): bf16 input + BN+ReLU, dinv-scaled out ------
__global__ __launch_bounds__(256) void k_gemm128_b(
    const unsigned short* __restrict__ inb, const unsigned short* __restrict__ Wt,
    unsigned short* __restrict__ outb,
    const float* __restrict__ bnsc, const float* __restrict__ bnsh,
    const float* __restrict__ dinv) {
    __shared__ unsigned short xs[32 * XPAD];
    __shared__ float dsv[32];
    const int tid = threadIdx.x;
    const int row0 = blockIdx.x * 32;
    if (tid < 32) dsv[tid] = dinv[row0 + tid];
    const unsigned short* inp = inb + (size_t)row0 * 128;
    for (int i = tid; i < 512; i += 256) {
        int r = i >> 4, c8 = (i & 15) * 8;
        short8v u = *(const short8v*)(inp + r * 128 + c8);
        short8v o;
        #pragma unroll
        for (int j = 0; j < 8; ++j) {
            float v = bf2f((unsigned short)u[j]);
            v = fmaxf(v * bnsc[c8 + j] + bnsh[c8 + j], 0.f);
            o[j] = (short)f2bf(v);
        }
        *(short8v*)&xs[r * XPAD + c8] = o;
    }
    __syncthreads();

    const int w = tid >> 6;
    const int L = tid & 63;
    const int l15 = L & 15;
    const int l4 = L >> 4;
    f32x4 acc[2][2] = {{{0.f, 0.f, 0.f, 0.f}, {0.f, 0.f, 0.f, 0.f}},
                       {{0.f, 0.f, 0.f, 0.f}, {0.f, 0.f, 0.f, 0.f}}};
    const unsigned short* Wb0 = Wt + (size_t)(w * 32 + l15) * 128;
    const unsigned short* Wb1 = Wt + (size_t)(w * 32 + 16 + l15) * 128;
    #pragma unroll
    for (int kk = 0; kk < 4; ++kk) {
        int k0 = kk * 32 + l4 * 8;
        short8v a0 = *(const short8v*)&xs[l15 * XPAD + k0];
        short8v a1 = *(const short8v*)&xs[(16 + l15) * XPAD + k0];
        short8v b0 = *(const short8v*)&Wb0[k0];
        short8v b1 = *(const short8v*)&Wb1[k0];
        acc[0][0] = __builtin_amdgcn_mfma_f32_16x16x32_bf16(a0, b0, acc[0][0], 0, 0, 0);
        acc[0][1] = __builtin_amdgcn_mfma_f32_16x16x32_bf16(a0, b1, acc[0][1], 0, 0, 0);
        acc[1][0] = __builtin_amdgcn_mfma_f32_16x16x32_bf16(a1, b0, acc[1][0], 0, 0, 0);
        acc[1][1] = __builtin_amdgcn_mfma_f32_16x16x32_bf16(a1, b1, acc[1][1], 0, 0, 0);
    }
    #pragma unroll
    for (int h = 0; h < 2; ++h)
        #pragma unroll
        for (int c = 0; c < 2; ++c) {
            int colg = w * 32 + c * 16 + l15;
            #pragma unroll
            for (int r = 0; r < 4; ++r) {
                int rl = h * 16 + l4 * 4 + r;
                outb[(size_t)(row0 + rl) * 128 + colg] = f2bf(acc[h][c][r] * dsv[rl]);
            }
        }
}

// ------- MFMA GEMM (layer 2): bf16 in + BN+ReLU, out[N,64] bf16 (cols 40+ = 0) ----
__global__ __launch_bounds__(256) void k_gemm40_mfma(
    const unsigned short* __restrict__ inb, const unsigned short* __restrict__ Wt,
    unsigned short* __restrict__ outb,
    const float* __restrict__ bnsc, const float* __restrict__ bnsh,
    const float* __restrict__ dinv) {
    __shared__ unsigned short xs[64 * XPAD];
    __shared__ float dsv[64];
    const int tid = threadIdx.x;
    const int row0 = blockIdx.x * 64;
    if (tid < 64) dsv[tid] = (row0 + tid < NN) ? dinv[row0 + tid] : 0.f;
    for (int i = tid; i < 1024; i += 256) {
        int r = i >> 4, c8 = (i & 15) * 8;
        short8v u = {0, 0, 0, 0, 0, 0, 0, 0};
        if (row0 + r < NN) u = *(const short8v*)(inb + (size_t)(row0 + r) * 128 + c8);
        short8v o;
        #pragma unroll
        for (int j = 0; j < 8; ++j) {
            float v = bf2f((unsigned short)u[j]);
            v = fmaxf(v * bnsc[c8 + j] + bnsh[c8 + j], 0.f);
            o[j] = (short)f2bf(v);
        }
        *(short8v*)&xs[r * XPAD + c8] = o;
    }
    __syncthreads();

    const int w = tid >> 6;
    const int L = tid & 63;
    const int l15 = L & 15;
    const int l4 = L >> 4;
    f32x4 acc[4] = {{0.f, 0.f, 0.f, 0.f}, {0.f, 0.f, 0.f, 0.f},
                    {0.f, 0.f, 0.f, 0.f}, {0.f, 0.f, 0.f, 0.f}};
    #pragma unroll
    for (int kk = 0; kk < 4; ++kk) {
        int k0 = kk * 32 + l4 * 8;
        short8v a = *(const short8v*)&xs[(w * 16 + l15) * XPAD + k0];
        #pragma unroll
        for (int cgi = 0; cgi < 4; ++cgi) {
            short8v b = *(const short8v*)&Wt[(size_t)(cgi * 16 + l15) * 128 + k0];
            acc[cgi] = __builtin_amdgcn_mfma_f32_16x16x32_bf16(a, b, acc[cgi], 0, 0, 0);
        }
    }
    #pragma unroll
    for (int cgi = 0; cgi < 4; ++cgi) {
        int colg = cgi * 16 + l15;
        #pragma unroll
        for (int r = 0; r < 4; ++r) {
            int rl = w * 16 + l4 * 4 + r;
            if (row0 + rl < NN)
                outb[(size_t)(row0 + rl) * 64 + colg] = f2bf(acc[cgi][r] * dsv[rl]);
        }
    }
}

// ---------------- CSR gather F=128: convergent shfl-idx, 16B row loads -----------
__global__ __launch_bounds__(256) void k_gather128c(
    const unsigned short* __restrict__ hb, const float* __restrict__ dinv,
    const int* __restrict__ rowptr, const int* __restrict__ cecol,
    const float* __restrict__ bias, unsigned short* __restrict__ aggb,
    float* __restrict__ stats2) {
    __shared__ float comb[4][256];
    const int w = threadIdx.x >> 6;
    const int lane = threadIdx.x & 63;
    const int g = lane >> 4;        // edge group 0..3
    const int q = lane & 15;        // column block: cols q*8..q*8+7
    const int node = blockIdx.x * 4 + w;   // NN % 4 == 0, grid exact
    const int co = q * 8;

    float acc[8] = {};
    const int e0 = rowptr[node];
    const int ne = rowptr[node + 1] - e0;       // wave-uniform
    for (int cb = 0; cb < ne; cb += 64) {       // wave-uniform chunk loop
        int idx = cecol[e0 + min(cb + lane, ne - 1)];   // coalesced, 64 idx/wave
        const int clim = min(ne - cb, 64);      // wave-uniform
        const int nfull = clim >> 4;            // full rounds of 16 edges
        int i = g;
        for (int r = 0; r < nfull; ++r, i += 16) {   // uniform trip count
            int s0 = __shfl(idx, i);
            int s1 = __shfl(idx, i + 4);
            int s2 = __shfl(idx, i + 8);
            int s3 = __shfl(idx, i + 12);
            short8v v0 = *(const short8v*)(hb + (size_t)s0 * 128 + co);
            short8v v1 = *(const short8v*)(hb + (size_t)s1 * 128 + co);
            short8v v2 = *(const short8v*)(hb + (size_t)s2 * 128 + co);
            short8v v3 = *(const short8v*)(hb + (size_t)s3 * 128 + co);
            #pragma unroll
            for (int j = 0; j < 8; ++j)
                acc[j] += (bf2f((unsigned short)v0[j]) + bf2f((unsigned short)v1[j]))
                        + (bf2f((unsigned short)v2[j]) + bf2f((unsigned short)v3[j]));
        }
        if (clim & 15) {                        // wave-uniform partial round
            const int last = clim - 1;
            int j0 = i, j1 = i + 4, j2 = i + 8, j3 = i + 12;
            int s0 = __shfl(idx, min(j0, last));     // convergent shfl, clamped
            int s1 = __shfl(idx, min(j1, last));
            int s2 = __shfl(idx, min(j2, last));
            int s3 = __shfl(idx, min(j3, last));
            short8v v0 = *(const short8v*)(hb + (size_t)s0 * 128 + co);
            short8v v1 = *(const short8v*)(hb + (size_t)s1 * 128 + co);
            short8v v2 = *(const short8v*)(hb + (size_t)s2 * 128 + co);
            short8v v3 = *(const short8v*)(hb + (size_t)s3 * 128 + co);
            if (j0 < clim) {
                #pragma unroll
                for (int j = 0; j < 8; ++j) acc[j] += bf2f((unsigned short)v0[j]);
            }
            if (j1 < clim) {
                #pragma unroll
                for (int j = 0; j < 8; ++j) acc[j] += bf2f((unsigned short)v1[j]);
            }
            if (j2 < clim) {
                #pragma unroll
                for (int j = 0; j < 8; ++j) acc[j] += bf2f((unsigned short)v2[j]);
            }
            if (j3 < clim) {
                #pragma unroll
                for (int j = 0; j < 8; ++j) acc[j] += bf2f((unsigned short)v3[j]);
            }
        }
    }
    if (g == 0) {   // self-loop row, added once (no shfl inside)
        short8v v = *(const short8v*)(hb + (size_t)node * 128 + co);
        #pragma unroll
        for (int j = 0; j < 8; ++j)
            acc[j] += bf2f((unsigned short)v[j]);
    }
    // cross-group butterfly (convergent): lanes {q, q+16, q+32, q+48} sum
    #pragma unroll
    for (int j = 0; j < 8; ++j) {
        acc[j] += __shfl_xor(acc[j], 16);
        acc[j] += __shfl_xor(acc[j], 32);
    }
    float dn = dinv[node];
    float fin[8];
    #pragma unroll
    for (int j = 0; j < 8; ++j)
        fin[j] = acc[j] * dn + bias[co + j];
    if (g == 0) {
        short8v ob;
        #pragma unroll
        for (int j = 0; j < 8; ++j) ob[j] = (short)f2bf(fin[j]);
        *(short8v*)(aggb + (size_t)node * 128 + co) = ob;
        float4 f0 = {fin[0], fin[1], fin[2], fin[3]};
        float4 f1 = {fin[4], fin[5], fin[6], fin[7]};
        *(float4*)&comb[w][co] = f0;
        *(float4*)&comb[w][co + 4] = f1;
    }
    if (g == 1) {
        float4 f0 = {fin[0] * fin[0], fin[1] * fin[1], fin[2] * fin[2], fin[3] * fin[3]};
        float4 f1 = {fin[4] * fin[4], fin[5] * fin[5], fin[6] * fin[6], fin[7] * fin[7]};
        *(float4*)&comb[w][128 + co] = f0;
        *(float4*)&comb[w][132 + co] = f1;
    }
    __syncthreads();
    int t = threadIdx.x;
    float v = comb[0][t] + comb[1][t] + comb[2][t] + comb[3][t];
    atomicAdd(&stats2[(blockIdx.x & 63) * 256 + t], v);
}

// ------- CSR gather F=40 (64-padded rows): 8 groups x 8 lanes, convergent shfl ----
__global__ __launch_bounds__(256) void k_gather40w(
    const unsigned short* __restrict__ hb, const float* __restrict__ dinv,
    const int* __restrict__ rowptr, const int* __restrict__ cecol,
    const float* __restrict__ bias, float* __restrict__ out) {
    const int w = threadIdx.x >> 6;
    const int lane = threadIdx.x & 63;
    const int g = lane >> 3;        // edge group 0..7
    const int q = lane & 7;         // cols q*8..q*8+7 (of 64-padded row)
    const int node = blockIdx.x * 4 + w;
    const int co = q * 8;

    float acc[8] = {};
    const int e0 = rowptr[node];
    const int ne = rowptr[node + 1] - e0;
    for (int cb = 0; cb < ne; cb += 64) {       // wave-uniform
        int idx = cecol[e0 + min(cb + lane, ne - 1)];
        const int clim = min(ne - cb, 64);
        const int nfull = clim >> 4;            // rounds of 16 (2 edges/group)
        int i = g;
        for (int r = 0; r < nfull; ++r, i += 16) {
            int s0 = __shfl(idx, i);
            int s1 = __shfl(idx, i + 8);
            short8v v0 = *(const short8v*)(hb + (size_t)s0 * 64 + co);
            short8v v1 = *(const short8v*)(hb + (size_t)s1 * 64 + co);
            #pragma unroll
            for (int j = 0; j < 8; ++j)
                acc[j] += bf2f((unsigned short)v0[j]) + bf2f((unsigned short)v1[j]);
        }
        if (clim & 15) {                        // wave-uniform partial round
            const int last = clim - 1;
            int j0 = i, j1 = i + 8;
            int s0 = __shfl(idx, min(j0, last));
            int s1 = __shfl(idx, min(j1, last));
            short8v v0 = *(const short8v*)(hb + (size_t)s0 * 64 + co);
            short8v v1 = *(const short8v*)(hb + (size_t)s1 * 64 + co);
            if (j0 < clim) {
                #pragma unroll
                for (int j = 0; j < 8; ++j) acc[j] += bf2f((unsigned short)v0[j]);
            }
            if (j1 < clim) {
                #pragma unroll
                for (int j = 0; j < 8; ++j) acc[j] += bf2f((unsigned short)v1[j]);
            }
        }
    }
    if (g == 0) {   // self-loop
        short8v v = *(const short8v*)(hb + (size_t)node * 64 + co);
        #pragma unroll
        for (int j = 0; j < 8; ++j)
            acc[j] += bf2f((unsigned short)v[j]);
    }
    #pragma unroll
    for (int j = 0; j < 8; ++j) {
        acc[j] += __shfl_xor(acc[j], 8);
        acc[j] += __shfl_xor(acc[j], 16);
        acc[j] += __shfl_xor(acc[j], 32);
    }
    if (g == 0 && co < 40) {        // q = 0..4 cover the 40 real cols
        float dn = dinv[node];
        float4 o0, o1;
        o0.x = acc[0] * dn + bias[co];
        o0.y = acc[1] * dn + bias[co + 1];
        o0.z = acc[2] * dn + bias[co + 2];
        o0.w = acc[3] * dn + bias[co + 3];
        o1.x = acc[4] * dn + bias[co + 4];
        o1.y = acc[5] * dn + bias[co + 5];
        o1.z = acc[6] * dn + bias[co + 6];
        o1.w = acc[7] * dn + bias[co + 7];
        float* op = out + (size_t)node * 40 + co;
        *(float4*)op = o0;
        *(float4*)(op + 4) = o1;
    }
}

// fold 64 stat copies + gamma/beta into scale/shift; re-zero stats2 for next use
__global__ void k_bnfinal2(float* __restrict__ stats2,
                           const float* __restrict__ gamma, const float* __restrict__ beta,
                           float* __restrict__ bnsc, float* __restrict__ bnsh) {
    int c = threadIdx.x;
    if (c >= 128) return;
    float s = 0.f, q = 0.f;
    for (int k = 0; k < 64; ++k) {
        s += stats2[k * 256 + c];
        q += stats2[k * 256 + 128 + c];
        stats2[k * 256 + c] = 0.f;
        stats2[k * 256 + 128 + c] = 0.f;
    }
    const float invn = 1.0f / (float)NN;
    float m = s * invn;
    float var = q * invn - m * m;
    float sc = gamma[c] * rsqrtf(var + EPS_BN);
    bnsc[c] = sc;
    bnsh[c] = beta[c] - m * sc;
}

extern "C" void kernel_launch(void* const* d_in, const int* in_sizes, int n_in,
                              void* d_out, int out_size, void* d_ws, size_t ws_size,
                              hipStream_t stream) {
    const float* x  = (const float*)d_in[0];
    const int*   ei = (const int*)d_in[1];
    const int*   src = ei;        // edge_index[0]
    const int*   dst = ei + NE;   // edge_index[1]
    const float* W0 = (const float*)d_in[2];
    const float* b0 = (const float*)d_in[3];
    const float* W1 = (const float*)d_in[4];
    const float* b1 = (const float*)d_in[5];
    const float* W2 = (const float*)d_in[6];
    const float* b2 = (const float*)d_in[7];
    const float* g0 = (const float*)d_in[8];
    const float* be0 = (const float*)d_in[9];
    const float* g1 = (const float*)d_in[10];
    const float* be1 = (const float*)d_in[11];
    float* out = (float*)d_out;

    // workspace layout (~68 MB)
    unsigned short* Hb   = (unsigned short*)d_ws;            // N*128 bf16 (gemm out, dinv-scaled)
    unsigned short* Ab   = Hb + (size_t)NN * 128;            // N*128 bf16 (gather out)
    unsigned short* H40  = Hb;                               // N*64 bf16 (aliases Hb)
    int*            part = (int*)(Ab + (size_t)NN * 128);    // NB*CAP int (packed dloc|src)
    int*            cecol = part + (size_t)NB * CAP;         // NE int
    float*          dinv = (float*)(cecol + NE);             // N
    float*          stats2 = dinv + NN;                      // 64*256
    float*          bnsc = stats2 + 64 * 256;                // 128
    float*          bnsh = bnsc + 128;                       // 128
    unsigned short* Wt0  = (unsigned short*)(bnsh + 128);    // 128*128 bf16
    unsigned short* Wt1  = Wt0 + 128 * 128;                  // 128*128 bf16
    unsigned short* Wt2  = Wt1 + 128 * 128;                  // 64*128 bf16
    int*            rowptr = (int*)(Wt2 + 64 * 128);         // N+1
    int*            cursors = rowptr + NN + 1;               // NB

    dim3 b256(256);
    int gPart = (NE + 4095) / 4096;          // 391

    // ---- CSR build (partition + fused bucket hist/scan/fill) ----
    k_init<<<64, b256, 0, stream>>>(stats2, cursors);
    k_part<<<gPart, b256, 0, stream>>>(src, dst, cursors, part);
    k_bucket<<<NB, b256, 0, stream>>>(cursors, part, rowptr, dinv, cecol);

    // ---- weight prep (fused) ----
    k_wconvall<<<160, b256, 0, stream>>>(W0, W1, W2, Wt0, Wt1, Wt2);

    int gG = NN / 4;   // 25000, exact

    // ---- layer 0 ----
    k_gemm128_f<<<NN / 32, b256, 0, stream>>>(x, Wt0, Hb, dinv);
    k_gather128c<<<gG, b256, 0, stream>>>(Hb, dinv, rowptr, cecol, b0, Ab, stats2);
    k_bnfinal2<<<1, 128, 0, stream>>>(stats2, g0, be0, bnsc, bnsh);

    // ---- layer 1 ----
    k_gemm128_b<<<NN / 32, b256, 0, stream>>>(Ab, Wt1, Hb, bnsc, bnsh, dinv);
    k_gather128c<<<gG, b256, 0, stream>>>(Hb, dinv, rowptr, cecol, b1, Ab, stats2);
    k_bnfinal2<<<1, 128, 0, stream>>>(stats2, g1, be1, bnsc, bnsh);

    // ---- layer 2 (64-col padded H40) ----
    k_gemm40_mfma<<<(NN + 63) / 64, b256, 0, stream>>>(Ab, Wt2, H40, bnsc, bnsh, dinv);
    k_gather40w<<<NN / 4, b256, 0, stream>>>(H40, dinv, rowptr, cecol, b2, out);
}

// Round 16
// 302.647 us; speedup vs baseline: 2.4789x; 1.2737x over previous
//
#include <hip/hip_runtime.h>

#define NN 100000
#define NE 1600000
#define EPS_BN 1e-5f
#define NB 250      // dst buckets (one block each in k_bucket)
#define BW 400      // nodes per bucket: NB*BW == NN
#define CAP 8192    // bucket capacity (avg 6400, ~22 sigma)

typedef __attribute__((ext_vector_type(8))) short short8v;
typedef __attribute__((ext_vector_type(4))) float f32x4;

__device__ __forceinline__ unsigned short f2bf(float f) {
    unsigned u = __float_as_uint(f);
    u += 0x7fff + ((u >> 16) & 1);          // RTNE
    return (unsigned short)(u >> 16);
}
__device__ __forceinline__ float bf2f(unsigned short h) {
    return __uint_as_float((unsigned)h << 16);
}

// ---------------- init: stats2 zero, cursors ----------------
__global__ void k_init(float* __restrict__ stats2, int* __restrict__ cursors) {
    int i = blockIdx.x * 256 + threadIdx.x;
    if (i < 64 * 256) stats2[i] = 0.f;
    if (i < NB) cursors[i] = i * CAP;
}

// Phase A: partition edges into 250 dst-range buckets; pack (dloc<<17)|src.
__global__ __launch_bounds__(256) void k_part(const int* __restrict__ src,
                                              const int* __restrict__ dst,
                                              int* __restrict__ cursors,
                                              int* __restrict__ part) {
    __shared__ int lh[4][256];    // per-wave hist, then per-wave fill cursor
    __shared__ int lo[4][256];    // per-wave base offset
    int t = threadIdx.x;
    int w = t >> 6;
    for (int i = t; i < 4 * 256; i += 256) ((int*)lh)[i] = 0;
    __syncthreads();
    int base = blockIdx.x * 4096;
    int pk[16], b[16];
    #pragma unroll 16
    for (int it = 0; it < 16; ++it) {
        int e = base + it * 256 + t;
        if (e < NE) {
            int d = dst[e];
            int s = src[e];
            b[it] = d / BW;
            pk[it] = ((d - b[it] * BW) << 17) | s;
            atomicAdd(&lh[w][b[it]], 1);
        } else b[it] = -1;
    }
    __syncthreads();
    if (t < NB) {
        int c0 = lh[0][t], c1 = lh[1][t], c2 = lh[2][t], c3 = lh[3][t];
        int tot = c0 + c1 + c2 + c3;
        int bb = atomicAdd(&cursors[t], tot);
        lo[0][t] = bb;
        lo[1][t] = bb + c0;
        lo[2][t] = bb + c0 + c1;
        lo[3][t] = bb + c0 + c1 + c2;
        lh[0][t] = 0; lh[1][t] = 0; lh[2][t] = 0; lh[3][t] = 0;
    }
    __syncthreads();
    #pragma unroll 16
    for (int it = 0; it < 16; ++it) {
        if (b[it] >= 0) {
            int pos = lo[w][b[it]] + atomicAdd(&lh[w][b[it]], 1);
            part[pos] = pk[it];
        }
    }
}

// Phase B+C fused, one block per bucket (250 blocks): LDS hist -> LDS scan
// (rowptr + dinv slice) -> LDS-cursor CSR fill of contiguous cecol slice.
__global__ __launch_bounds__(256) void k_bucket(const int* __restrict__ cursors,
                                                const int* __restrict__ part,
                                                int* __restrict__ rowptr,
                                                float* __restrict__ dinv,
                                                int* __restrict__ cecol) {
    __shared__ int hist[BW];      // 1.6 KB
    __shared__ int tsum[256];
    __shared__ int bsum[256];
    const int b = blockIdx.x;
    const int t = threadIdx.x;
    // bucket sizes -> LDS scan for global base of this bucket
    int cnt_t = (t < NB) ? (cursors[t] - t * CAP) : 0;
    bsum[t] = cnt_t;
    for (int i = t; i < BW; i += 256) hist[i] = 0;
    __syncthreads();
    for (int off = 1; off < 256; off <<= 1) {
        int v = (t >= off) ? bsum[t - off] : 0;
        __syncthreads();
        bsum[t] += v;
        __syncthreads();
    }
    const int n = cursors[b] - b * CAP;
    const int base = (b > 0) ? bsum[b - 1] : 0;
    const int* p = part + (size_t)b * CAP;
    // histogram
    for (int i = t; i < n; i += 256)
        atomicAdd(&hist[p[i] >> 17], 1);
    __syncthreads();
    // per-thread 2-entry segment + block scan
    const int s0 = t * 2;
    int run = 0;
    if (s0 < BW) {
        run = hist[s0];
        if (s0 + 1 < BW) run += hist[s0 + 1];
    }
    tsum[t] = run;
    __syncthreads();
    for (int off = 1; off < 256; off <<= 1) {
        int v = (t >= off) ? tsum[t - off] : 0;
        __syncthreads();
        tsum[t] += v;
        __syncthreads();
    }
    int pref = base + ((t > 0) ? tsum[t - 1] : 0);
    if (s0 < BW) {
        int c0 = hist[s0];
        hist[s0] = pref;
        rowptr[b * BW + s0] = pref;
        dinv[b * BW + s0] = rsqrtf((float)(c0 + 1));     // +1 self-loop
        int pref1 = pref + c0;
        if (s0 + 1 < BW) {
            int c1 = hist[s0 + 1];
            hist[s0 + 1] = pref1;
            rowptr[b * BW + s0 + 1] = pref1;
            dinv[b * BW + s0 + 1] = rsqrtf((float)(c1 + 1));
        }
    }
    if (b == NB - 1 && t == 0) rowptr[NN] = NE;
    __syncthreads();
    // fill
    for (int i = t; i < n; i += 256) {
        int u = p[i];
        int pos = atomicAdd(&hist[u >> 17], 1);
        cecol[pos] = u & 0x1FFFF;
    }
}

// ---------------- fused weight convert: W0,W1 -> Wt[c][k]; W2 -> [64][128] padded --
__global__ void k_wconvall(const float* __restrict__ W0, const float* __restrict__ W1,
                           const float* __restrict__ W2,
                           unsigned short* __restrict__ Wt0,
                           unsigned short* __restrict__ Wt1,
                           unsigned short* __restrict__ Wt2) {
    int idx = blockIdx.x * 256 + threadIdx.x;
    if (idx < 16384) {
        int k = idx >> 7, c = idx & 127;
        Wt0[c * 128 + k] = f2bf(W0[idx]);
    } else if (idx < 32768) {
        int j = idx - 16384;
        int k = j >> 7, c = j & 127;
        Wt1[c * 128 + k] = f2bf(W1[j]);
    } else if (idx < 32768 + 8192) {
        int j = idx - 32768;
        int c = j >> 7, k = j & 127;
        Wt2[j] = (c < 40) ? f2bf(W2[k * 40 + c]) : (unsigned short)0;
    }
}

#define XPAD 136   // LDS row stride in ushorts: 272B = 68 words, 68%32=4 -> 2-way max

// ---------------- MFMA GEMM (layer 0): f32 input, out rows pre-scaled by dinv ------
__global__ __launch_bounds__(256) void k_gemm128_f(
    const float* __restrict__ in, const unsigned short* __restrict__ Wt,
    unsigned short* __restrict__ outb, const float* __restrict__ dinv) {
    __shared__ unsigned short xs[32 * XPAD];
    __shared__ float dsv[32];
    const int tid = threadIdx.x;
    const int row0 = blockIdx.x * 32;
    if (tid < 32) dsv[tid] = dinv[row0 + tid];
    for (int i = tid; i < 1024; i += 256) {
        float4 v = ((const float4*)(in + (size_t)row0 * 128))[i];
        int c4 = (i & 31) * 4;
        ushort4 b;
        b.x = f2bf(v.x); b.y = f2bf(v.y); b.z = f2bf(v.z); b.w = f2bf(v.w);
        *(ushort4*)&xs[(i >> 5) * XPAD + c4] = b;
    }
    __syncthreads();

    const int w = tid >> 6;
    const int L = tid & 63;
    const int l15 = L & 15;
    const int l4 = L >> 4;
    f32x4 acc[2][2] = {{{0.f, 0.f, 0.f, 0.f}, {0.f, 0.f, 0.f, 0.f}},
                       {{0.f, 0.f, 0.f, 0.f}, {0.f, 0.f, 0.f, 0.f}}};
    const unsigned short* Wb0 = Wt + (size_t)(w * 32 + l15) * 128;
    const unsigned short* Wb1 = Wt + (size_t)(w * 32 + 16 + l15) * 128;
    #pragma unroll
    for (int kk = 0; kk < 4; ++kk) {
        int k0 = kk * 32 + l4 * 8;
        short8v a0 = *(const short8v*)&xs[l15 * XPAD + k0];
        short8v a1 = *(const short8v*)&xs[(16 + l15) * XPAD + k0];
        short8v b0 = *(const short8v*)&Wb0[k0];
        short8v b1 = *(const short8v*)&Wb1[k0];
        acc[0][0] = __builtin_amdgcn_mfma_f32_16x16x32_bf16(a0, b0, acc[0][0], 0, 0, 0);
        acc[0][1] = __builtin_amdgcn_mfma_f32_16x16x32_bf16(a0, b1, acc[0][1], 0, 0, 0);
        acc[1][0] = __builtin_amdgcn_mfma_f32_16x16x32_bf16(a1, b0, acc[1][0], 0, 0, 0);
        acc[1][1] = __builtin_amdgcn_mfma_f32_16x16x32_bf16(a1, b1, acc[1][1], 0, 0, 0);
    }
    #pragma unroll
    for (int h = 0; h < 2; ++h)
        #pragma unroll
        for (int c = 0; c < 2; ++c) {
            int colg = w * 32 + c * 16 + l15;
            #pragma unroll
            for (int r = 0; r < 4; ++r) {
                int rl = h * 16 + l4 * 4 + r;
                outb[(size_t)(row0 + rl) * 128 + colg] = f2bf(acc[h][c][r] * dsv[rl]);
            }
        }
}

// ---------------- MFMA GEMM (layer 1): bf16 input + BN+ReLU, dinv-scaled out ------
__global__ __launch_bounds__(256) void k_gemm128_b(
    const unsigned short* __restrict__ inb, const unsigned short* __restrict__ Wt,
    unsigned short* __restrict__ outb,
    const float* __restrict__ bnsc, const float* __restrict__ bnsh,
    const float* __restrict__ dinv) {
    __shared__ unsigned short xs[32 * XPAD];
    __shared__ float dsv[32];
    const int tid = threadIdx.x;
    const int row0 = blockIdx.x * 32;
    if (tid < 32) dsv[tid] = dinv[row0 + tid];
    const unsigned short* inp = inb + (size_t)row0 * 128;
    for (int i = tid; i < 512; i += 256) {
        int r = i >> 4, c8 = (i & 15) * 8;
        short8v u = *(const short8v*)(inp + r * 128 + c8);
        short8v o;
        #pragma unroll
        for (int j = 0; j < 8; ++j) {
            float v = bf2f((unsigned short)u[j]);
            v = fmaxf(v * bnsc[c8 + j] + bnsh[c8 + j], 0.f);
            o[j] = (short)f2bf(v);
        }
        *(short8v*)&xs[r * XPAD + c8] = o;
    }
    __syncthreads();

    const int w = tid >> 6;
    const int L = tid & 63;
    const int l15 = L & 15;
    const int l4 = L >> 4;
    f32x4 acc[2][2] = {{{0.f, 0.f, 0.f, 0.f}, {0.f, 0.f, 0.f, 0.f}},
                       {{0.f, 0.f, 0.f, 0.f}, {0.f, 0.f, 0.f, 0.f}}};
    const unsigned short* Wb0 = Wt + (size_t)(w * 32 + l15) * 128;
    const unsigned short* Wb1 = Wt + (size_t)(w * 32 + 16 + l15) * 128;
    #pragma unroll
    for (int kk = 0; kk < 4; ++kk) {
        int k0 = kk * 32 + l4 * 8;
        short8v a0 = *(const short8v*)&xs[l15 * XPAD + k0];
        short8v a1 = *(const short8v*)&xs[(16 + l15) * XPAD + k0];
        short8v b0 = *(const short8v*)&Wb0[k0];
        short8v b1 = *(const short8v*)&Wb1[k0];
        acc[0][0] = __builtin_amdgcn_mfma_f32_16x16x32_bf16(a0, b0, acc[0][0], 0, 0, 0);
        acc[0][1] = __builtin_amdgcn_mfma_f32_16x16x32_bf16(a0, b1, acc[0][1], 0, 0, 0);
        acc[1][0] = __builtin_amdgcn_mfma_f32_16x16x32_bf16(a1, b0, acc[1][0], 0, 0, 0);
        acc[1][1] = __builtin_amdgcn_mfma_f32_16x16x32_bf16(a1, b1, acc[1][1], 0, 0, 0);
    }
    #pragma unroll
    for (int h = 0; h < 2; ++h)
        #pragma unroll
        for (int c = 0; c < 2; ++c) {
            int colg = w * 32 + c * 16 + l15;
            #pragma unroll
            for (int r = 0; r < 4; ++r) {
                int rl = h * 16 + l4 * 4 + r;
                outb[(size_t)(row0 + rl) * 128 + colg] = f2bf(acc[h][c][r] * dsv[rl]);
            }
        }
}

// ------- MFMA GEMM (layer 2): bf16 in + BN+ReLU, out[N,64] bf16 (cols 40+ = 0) ----
__global__ __launch_bounds__(256) void k_gemm40_mfma(
    const unsigned short* __restrict__ inb, const unsigned short* __restrict__ Wt,
    unsigned short* __restrict__ outb,
    const float* __restrict__ bnsc, const float* __restrict__ bnsh,
    const float* __restrict__ dinv) {
    __shared__ unsigned short xs[64 * XPAD];
    __shared__ float dsv[64];
    const int tid = threadIdx.x;
    const int row0 = blockIdx.x * 64;
    if (tid < 64) dsv[tid] = (row0 + tid < NN) ? dinv[row0 + tid] : 0.f;
    for (int i = tid; i < 1024; i += 256) {
        int r = i >> 4, c8 = (i & 15) * 8;
        short8v u = {0, 0, 0, 0, 0, 0, 0, 0};
        if (row0 + r < NN) u = *(const short8v*)(inb + (size_t)(row0 + r) * 128 + c8);
        short8v o;
        #pragma unroll
        for (int j = 0; j < 8; ++j) {
            float v = bf2f((unsigned short)u[j]);
            v = fmaxf(v * bnsc[c8 + j] + bnsh[c8 + j], 0.f);
            o[j] = (short)f2bf(v);
        }
        *(short8v*)&xs[r * XPAD + c8] = o;
    }
    __syncthreads();

    const int w = tid >> 6;
    const int L = tid & 63;
    const int l15 = L & 15;
    const int l4 = L >> 4;
    f32x4 acc[4] = {{0.f, 0.f, 0.f, 0.f}, {0.f, 0.f, 0.f, 0.f},
                    {0.f, 0.f, 0.f, 0.f}, {0.f, 0.f, 0.f, 0.f}};
    #pragma unroll
    for (int kk = 0; kk < 4; ++kk) {
        int k0 = kk * 32 + l4 * 8;
        short8v a = *(const short8v*)&xs[(w * 16 + l15) * XPAD + k0];
        #pragma unroll
        for (int cgi = 0; cgi < 4; ++cgi) {
            short8v b = *(const short8v*)&Wt[(size_t)(cgi * 16 + l15) * 128 + k0];
            acc[cgi] = __builtin_amdgcn_mfma_f32_16x16x32_bf16(a, b, acc[cgi], 0, 0, 0);
        }
    }
    #pragma unroll
    for (int cgi = 0; cgi < 4; ++cgi) {
        int colg = cgi * 16 + l15;
        #pragma unroll
        for (int r = 0; r < 4; ++r) {
            int rl = w * 16 + l4 * 4 + r;
            if (row0 + rl < NN)
                outb[(size_t)(row0 + rl) * 64 + colg] = f2bf(acc[cgi][r] * dsv[rl]);
        }
    }
}

// ---------------- CSR gather F=128: convergent shfl-idx, 16B row loads -----------
__global__ __launch_bounds__(256) void k_gather128c(
    const unsigned short* __restrict__ hb, const float* __restrict__ dinv,
    const int* __restrict__ rowptr, const int* __restrict__ cecol,
    const float* __restrict__ bias, unsigned short* __restrict__ aggb,
    float* __restrict__ stats2) {
    __shared__ float comb[4][256];
    const int w = threadIdx.x >> 6;
    const int lane = threadIdx.x & 63;
    const int g = lane >> 4;        // edge group 0..3
    const int q = lane & 15;        // column block: cols q*8..q*8+7
    const int node = blockIdx.x * 4 + w;   // NN % 4 == 0, grid exact
    const int co = q * 8;

    float acc[8] = {};
    const int e0 = rowptr[node];
    const int ne = rowptr[node + 1] - e0;       // wave-uniform
    for (int cb = 0; cb < ne; cb += 64) {       // wave-uniform chunk loop
        int idx = cecol[e0 + min(cb + lane, ne - 1)];   // coalesced, 64 idx/wave
        const int clim = min(ne - cb, 64);      // wave-uniform
        const int nfull = clim >> 4;            // full rounds of 16 edges
        int i = g;
        for (int r = 0; r < nfull; ++r, i += 16) {   // uniform trip count
            int s0 = __shfl(idx, i);
            int s1 = __shfl(idx, i + 4);
            int s2 = __shfl(idx, i + 8);
            int s3 = __shfl(idx, i + 12);
            short8v v0 = *(const short8v*)(hb + (size_t)s0 * 128 + co);
            short8v v1 = *(const short8v*)(hb + (size_t)s1 * 128 + co);
            short8v v2 = *(const short8v*)(hb + (size_t)s2 * 128 + co);
            short8v v3 = *(const short8v*)(hb + (size_t)s3 * 128 + co);
            #pragma unroll
            for (int j = 0; j < 8; ++j)
                acc[j] += (bf2f((unsigned short)v0[j]) + bf2f((unsigned short)v1[j]))
                        + (bf2f((unsigned short)v2[j]) + bf2f((unsigned short)v3[j]));
        }
        if (clim & 15) {                        // wave-uniform partial round
            const int last = clim - 1;
            int j0 = i, j1 = i + 4, j2 = i + 8, j3 = i + 12;
            int s0 = __shfl(idx, min(j0, last));     // convergent shfl, clamped
            int s1 = __shfl(idx, min(j1, last));
            int s2 = __shfl(idx, min(j2, last));
            int s3 = __shfl(idx, min(j3, last));
            short8v v0 = *(const short8v*)(hb + (size_t)s0 * 128 + co);
            short8v v1 = *(const short8v*)(hb + (size_t)s1 * 128 + co);
            short8v v2 = *(const short8v*)(hb + (size_t)s2 * 128 + co);
            short8v v3 = *(const short8v*)(hb + (size_t)s3 * 128 + co);
            if (j0 < clim) {
                #pragma unroll
                for (int j = 0; j < 8; ++j) acc[j] += bf2f((unsigned short)v0[j]);
            }
            if (j1 < clim) {
                #pragma unroll
                for (int j = 0; j < 8; ++j) acc[j] += bf2f((unsigned short)v1[j]);
            }
            if (j2 < clim) {
                #pragma unroll
                for (int j = 0; j < 8; ++j) acc[j] += bf2f((unsigned short)v2[j]);
            }
            if (j3 < clim) {
                #pragma unroll
                for (int j = 0; j < 8; ++j) acc[j] += bf2f((unsigned short)v3[j]);
            }
        }
    }
    if (g == 0) {   // self-loop row, added once (no shfl inside)
        short8v v = *(const short8v*)(hb + (size_t)node * 128 + co);
        #pragma unroll
        for (int j = 0; j < 8; ++j)
            acc[j] += bf2f((unsigned short)v[j]);
    }
    // cross-group butterfly (convergent): lanes {q, q+16, q+32, q+48} sum
    #pragma unroll
    for (int j = 0; j < 8; ++j) {
        acc[j] += __shfl_xor(acc[j], 16);
        acc[j] += __shfl_xor(acc[j], 32);
    }
    float dn = dinv[node];
    float fin[8];
    #pragma unroll
    for (int j = 0; j < 8; ++j)
        fin[j] = acc[j] * dn + bias[co + j];
    if (g == 0) {
        short8v ob;
        #pragma unroll
        for (int j = 0; j < 8; ++j) ob[j] = (short)f2bf(fin[j]);
        *(short8v*)(aggb + (size_t)node * 128 + co) = ob;
        float4 f0 = {fin[0], fin[1], fin[2], fin[3]};
        float4 f1 = {fin[4], fin[5], fin[6], fin[7]};
        *(float4*)&comb[w][co] = f0;
        *(float4*)&comb[w][co + 4] = f1;
    }
    if (g == 1) {
        float4 f0 = {fin[0] * fin[0], fin[1] * fin[1], fin[2] * fin[2], fin[3] * fin[3]};
        float4 f1 = {fin[4] * fin[4], fin[5] * fin[5], fin[6] * fin[6], fin[7] * fin[7]};
        *(float4*)&comb[w][128 + co] = f0;
        *(float4*)&comb[w][132 + co] = f1;
    }
    __syncthreads();
    int t = threadIdx.x;
    float v = comb[0][t] + comb[1][t] + comb[2][t] + comb[3][t];
    atomicAdd(&stats2[(blockIdx.x & 63) * 256 + t], v);
}

// ------- CSR gather F=40 (64-padded rows): 8 groups x 8 lanes, convergent shfl ----
__global__ __launch_bounds__(256) void k_gather40w(
    const unsigned short* __restrict__ hb, const float* __restrict__ dinv,
    const int* __restrict__ rowptr, const int* __restrict__ cecol,
    const float* __restrict__ bias, float* __restrict__ out) {
    const int w = threadIdx.x >> 6;
    const int lane = threadIdx.x & 63;
    const int g = lane >> 3;        // edge group 0..7
    const int q = lane & 7;         // cols q*8..q*8+7 (of 64-padded row)
    const int node = blockIdx.x * 4 + w;
    const int co = q * 8;

    float acc[8] = {};
    const int e0 = rowptr[node];
    const int ne = rowptr[node + 1] - e0;
    for (int cb = 0; cb < ne; cb += 64) {       // wave-uniform
        int idx = cecol[e0 + min(cb + lane, ne - 1)];
        const int clim = min(ne - cb, 64);
        const int nfull = clim >> 4;            // rounds of 16 (2 edges/group)
        int i = g;
        for (int r = 0; r < nfull; ++r, i += 16) {
            int s0 = __shfl(idx, i);
            int s1 = __shfl(idx, i + 8);
            short8v v0 = *(const short8v*)(hb + (size_t)s0 * 64 + co);
            short8v v1 = *(const short8v*)(hb + (size_t)s1 * 64 + co);
            #pragma unroll
            for (int j = 0; j < 8; ++j)
                acc[j] += bf2f((unsigned short)v0[j]) + bf2f((unsigned short)v1[j]);
        }
        if (clim & 15) {                        // wave-uniform partial round
            const int last = clim - 1;
            int j0 = i, j1 = i + 8;
            int s0 = __shfl(idx, min(j0, last));
            int s1 = __shfl(idx, min(j1, last));
            short8v v0 = *(const short8v*)(hb + (size_t)s0 * 64 + co);
            short8v v1 = *(const short8v*)(hb + (size_t)s1 * 64 + co);
            if (j0 < clim) {
                #pragma unroll
                for (int j = 0; j < 8; ++j) acc[j] += bf2f((unsigned short)v0[j]);
            }
            if (j1 < clim) {
                #pragma unroll
                for (int j = 0; j < 8; ++j) acc[j] += bf2f((unsigned short)v1[j]);
            }
        }
    }
    if (g == 0) {   // self-loop
        short8v v = *(const short8v*)(hb + (size_t)node * 64 + co);
        #pragma unroll
        for (int j = 0; j < 8; ++j)
            acc[j] += bf2f((unsigned short)v[j]);
    }
    #pragma unroll
    for (int j = 0; j < 8; ++j) {
        acc[j] += __shfl_xor(acc[j], 8);
        acc[j] += __shfl_xor(acc[j], 16);
        acc[j] += __shfl_xor(acc[j], 32);
    }
    if (g == 0 && co < 40) {        // q = 0..4 cover the 40 real cols
        float dn = dinv[node];
        float4 o0, o1;
        o0.x = acc[0] * dn + bias[co];
        o0.y = acc[1] * dn + bias[co + 1];
        o0.z = acc[2] * dn + bias[co + 2];
        o0.w = acc[3] * dn + bias[co + 3];
        o1.x = acc[4] * dn + bias[co + 4];
        o1.y = acc[5] * dn + bias[co + 5];
        o1.z = acc[6] * dn + bias[co + 6];
        o1.w = acc[7] * dn + bias[co + 7];
        float* op = out + (size_t)node * 40 + co;
        *(float4*)op = o0;
        *(float4*)(op + 4) = o1;
    }
}

// fold 64 stat copies + gamma/beta into scale/shift; re-zero stats2 for next use
__global__ void k_bnfinal2(float* __restrict__ stats2,
                           const float* __restrict__ gamma, const float* __restrict__ beta,
                           float* __restrict__ bnsc, float* __restrict__ bnsh) {
    int c = threadIdx.x;
    if (c >= 128) return;
    float s = 0.f, q = 0.f;
    for (int k = 0; k < 64; ++k) {
        s += stats2[k * 256 + c];
        q += stats2[k * 256 + 128 + c];
        stats2[k * 256 + c] = 0.f;
        stats2[k * 256 + 128 + c] = 0.f;
    }
    const float invn = 1.0f / (float)NN;
    float m = s * invn;
    float var = q * invn - m * m;
    float sc = gamma[c] * rsqrtf(var + EPS_BN);
    bnsc[c] = sc;
    bnsh[c] = beta[c] - m * sc;
}

extern "C" void kernel_launch(void* const* d_in, const int* in_sizes, int n_in,
                              void* d_out, int out_size, void* d_ws, size_t ws_size,
                              hipStream_t stream) {
    const float* x  = (const float*)d_in[0];
    const int*   ei = (const int*)d_in[1];
    const int*   src = ei;        // edge_index[0]
    const int*   dst = ei + NE;   // edge_index[1]
    const float* W0 = (const float*)d_in[2];
    const float* b0 = (const float*)d_in[3];
    const float* W1 = (const float*)d_in[4];
    const float* b1 = (const float*)d_in[5];
    const float* W2 = (const float*)d_in[6];
    const float* b2 = (const float*)d_in[7];
    const float* g0 = (const float*)d_in[8];
    const float* be0 = (const float*)d_in[9];
    const float* g1 = (const float*)d_in[10];
    const float* be1 = (const float*)d_in[11];
    float* out = (float*)d_out;

    // workspace layout (~70 MB)
    unsigned short* Hb   = (unsigned short*)d_ws;            // N*128 bf16 (gemm out, dinv-scaled)
    unsigned short* Ab   = Hb + (size_t)NN * 128;            // N*128 bf16 (gather out)
    unsigned short* H40  = Hb;                               // N*64 bf16 (aliases Hb)
    int*            part = (int*)(Ab + (size_t)NN * 128);    // NB*CAP int (packed dloc|src)
    int*            cecol = part + (size_t)NB * CAP;         // NE int
    float*          dinv = (float*)(cecol + NE);             // N
    float*          stats2 = dinv + NN;                      // 64*256
    float*          bnsc = stats2 + 64 * 256;                // 128
    float*          bnsh = bnsc + 128;                       // 128
    unsigned short* Wt0  = (unsigned short*)(bnsh + 128);    // 128*128 bf16
    unsigned short* Wt1  = Wt0 + 128 * 128;                  // 128*128 bf16
    unsigned short* Wt2  = Wt1 + 128 * 128;                  // 64*128 bf16
    int*            rowptr = (int*)(Wt2 + 64 * 128);         // N+1
    int*            cursors = rowptr + NN + 1;               // NB

    dim3 b256(256);
    int gPart = (NE + 4095) / 4096;          // 391

    // ---- CSR build (partition + fused bucket hist/scan/fill, 250 blocks) ----
    k_init<<<64, b256, 0, stream>>>(stats2, cursors);
    k_part<<<gPart, b256, 0, stream>>>(src, dst, cursors, part);
    k_bucket<<<NB, b256, 0, stream>>>(cursors, part, rowptr, dinv, cecol);

    // ---- weight prep (fused) ----
    k_wconvall<<<160, b256, 0, stream>>>(W0, W1, W2, Wt0, Wt1, Wt2);

    int gG = NN / 4;   // 25000, exact

    // ---- layer 0 ----
    k_gemm128_f<<<NN / 32, b256, 0, stream>>>(x, Wt0, Hb, dinv);
    k_gather128c<<<gG, b256, 0, stream>>>(Hb, dinv, rowptr, cecol, b0, Ab, stats2);
    k_bnfinal2<<<1, 128, 0, stream>>>(stats2, g0, be0, bnsc, bnsh);

    // ---- layer 1 ----
    k_gemm128_b<<<NN / 32, b256, 0, stream>>>(Ab, Wt1, Hb, bnsc, bnsh, dinv);
    k_gather128c<<<gG, b256, 0, stream>>>(Hb, dinv, rowptr, cecol, b1, Ab, stats2);
    k_bnfinal2<<<1, 128, 0, stream>>>(stats2, g1, be1, bnsc, bnsh);

    // ---- layer 2 (64-col padded H40) ----
    k_gemm40_mfma<<<(NN + 63) / 64, b256, 0, stream>>>(Ab, Wt2, H40, bnsc, bnsh, dinv);
    k_gather40w<<<NN / 4, b256, 0, stream>>>(H40, dinv, rowptr, cecol, b2, out);
}